// Round 1
// baseline (1449.405 us; speedup 1.0000x reference)
//
#include <hip/hip_runtime.h>

// Vector Quantizer: N=32768 vectors of D=256, K=4096 codes.
// inputs  d_in[0]: float32 [32768, 256]   (reshaped (32,32,32,256))
// emb     d_in[1]: float32 [256, 4096]    (E[d][k], row-major)
// d_out: [8388608 floats e_k] + [1 float loss]
//
// Pipeline:
//   1) esq_kernel:      esq[k] = sum_d E[d][k]^2
//   2) dist_argmin:     per (128-row tile, 1024-code slice): running argmin of
//                       (esq[k] - 2 x.e_k), fp32 register-tiled 8x8
//   3) gather_loss:     final 4-way argmin per row, gather E[:,idx] -> out,
//                       per-block loss partial sums (deterministic)
//   4) finalize:        deterministic tree-reduce partials -> loss

#define N_ROWS 32768
#define DIM 256
#define K_CODES 4096
#define BM 128
#define BK 128
#define NKSLICE 4
#define KSLICE (K_CODES / NKSLICE)   // 1024
#define GATHER_BLOCKS 512

// ---------------- ws layout (bytes) ----------------
// [0,        16384)   esq      float[4096]
// [16384,   540672)   candv    float[32768*4]
// [540672, 1064960)   candi    int  [32768*4]
// [1064960,1067008)   partials float[512]
#define WS_ESQ_OFF      0
#define WS_CANDV_OFF    16384
#define WS_CANDI_OFF    540672
#define WS_PART_OFF     1064960

__global__ void esq_kernel(const float* __restrict__ E, float* __restrict__ esq) {
    __shared__ float red[16][17];
    int t = threadIdx.x;
    int kk = t & 15, dg = t >> 4;
    int k = blockIdx.x * 16 + kk;
    float a = 0.f;
#pragma unroll
    for (int it = 0; it < 16; ++it) {
        float e = E[(dg + it * 16) * K_CODES + k];
        a = fmaf(e, e, a);
    }
    red[dg][kk] = a;
    __syncthreads();
    if (t < 16) {
        float s = 0.f;
#pragma unroll
        for (int g = 0; g < 16; ++g) s += red[g][t];
        esq[blockIdx.x * 16 + t] = s;
    }
}

__global__ void dist_argmin(const float* __restrict__ X, const float* __restrict__ E,
                            const float* __restrict__ esq,
                            float* __restrict__ candv, int* __restrict__ candi) {
    __shared__ float Xs[8][BM];   // 4 KB, transposed: Xs[d][row]
    __shared__ float Es[8][BK];   // 4 KB: Es[d][col]
    const int t = threadIdx.x;
    const int tx = t & 15;        // col group
    const int ty = t >> 4;        // row group
    const int rowbase = blockIdx.x * BM;
    const int ks = blockIdx.y;    // 0..3

    float minv[8];
    int   mini[8];
#pragma unroll
    for (int i = 0; i < 8; ++i) { minv[i] = 3.4e38f; mini[i] = 0; }

    for (int kt = 0; kt < KSLICE / BK; ++kt) {
        const int kbase = ks * KSLICE + kt * BK;
        float acc[8][8];
#pragma unroll
        for (int i = 0; i < 8; ++i)
#pragma unroll
            for (int j = 0; j < 8; ++j) acc[i][j] = 0.f;

        for (int dc = 0; dc < DIM / 8; ++dc) {
            const int d0 = dc * 8;
            // stage X tile [128 rows][8 d], transposed into Xs[d][row]
            {
                const int row = t >> 1;
                const int dsl = (t & 1) * 4;
                const float4 xv = *(const float4*)(X + (size_t)(rowbase + row) * DIM + d0 + dsl);
                Xs[dsl + 0][row] = xv.x;
                Xs[dsl + 1][row] = xv.y;
                Xs[dsl + 2][row] = xv.z;
                Xs[dsl + 3][row] = xv.w;
            }
            // stage E tile [8 d][128 cols]
            {
                const int dr = t >> 5;
                const int c4 = (t & 31) * 4;
                const float4 ev = *(const float4*)(E + (size_t)(d0 + dr) * K_CODES + kbase + c4);
                *(float4*)&Es[dr][c4] = ev;
            }
            __syncthreads();
#pragma unroll
            for (int d = 0; d < 8; ++d) {
                float xr[8], er[8];
                *(float4*)&xr[0] = *(const float4*)&Xs[d][ty * 8];
                *(float4*)&xr[4] = *(const float4*)&Xs[d][ty * 8 + 4];
                *(float4*)&er[0] = *(const float4*)&Es[d][tx * 8];
                *(float4*)&er[4] = *(const float4*)&Es[d][tx * 8 + 4];
#pragma unroll
                for (int i = 0; i < 8; ++i)
#pragma unroll
                    for (int j = 0; j < 8; ++j)
                        acc[i][j] = fmaf(xr[i], er[j], acc[i][j]);
            }
            __syncthreads();
        }

        // epilogue: dist = esq[k] - 2*dot ; running argmin (ascending k, strict <)
        float eq[8];
        *(float4*)&eq[0] = *(const float4*)(esq + kbase + tx * 8);
        *(float4*)&eq[4] = *(const float4*)(esq + kbase + tx * 8 + 4);
#pragma unroll
        for (int i = 0; i < 8; ++i) {
#pragma unroll
            for (int j = 0; j < 8; ++j) {
                const float dist = fmaf(-2.f, acc[i][j], eq[j]);
                if (dist < minv[i]) { minv[i] = dist; mini[i] = kbase + tx * 8 + j; }
            }
        }
    }

    // cross-lane argmin over the 16 tx lanes (same rows), first-index tie-break
#pragma unroll
    for (int i = 0; i < 8; ++i) {
        float v = minv[i];
        int   id = mini[i];
#pragma unroll
        for (int m = 8; m >= 1; m >>= 1) {
            const float v2 = __shfl_xor(v, m, 64);
            const int   i2 = __shfl_xor(id, m, 64);
            if (v2 < v || (v2 == v && i2 < id)) { v = v2; id = i2; }
        }
        minv[i] = v; mini[i] = id;
    }
    if (tx == 0) {
#pragma unroll
        for (int i = 0; i < 8; ++i) {
            const int row = rowbase + ty * 8 + i;
            candv[row * NKSLICE + ks] = minv[i];
            candi[row * NKSLICE + ks] = mini[i];
        }
    }
}

__global__ void gather_loss(const float* __restrict__ X, const float* __restrict__ E,
                            const float* __restrict__ candv, const int* __restrict__ candi,
                            float* __restrict__ out, float* __restrict__ partials) {
    const int w = threadIdx.x >> 6;   // wave 0..3
    const int l = threadIdx.x & 63;   // lane
    const int rowbase = blockIdx.x * (N_ROWS / GATHER_BLOCKS);  // 64 rows/block
    float lsum = 0.f;

    for (int rr = w; rr < N_ROWS / GATHER_BLOCKS; rr += 4) {
        const int row = rowbase + rr;
        // final 4-way argmin (all lanes redundantly; broadcast reads)
        float bv = candv[row * NKSLICE];
        int   bi = candi[row * NKSLICE];
#pragma unroll
        for (int s = 1; s < NKSLICE; ++s) {
            const float v = candv[row * NKSLICE + s];
            const int  id = candi[row * NKSLICE + s];
            if (v < bv || (v == bv && id < bi)) { bv = v; bi = id; }
        }
        const float4 x = *(const float4*)(X + (size_t)row * DIM + l * 4);
        const float q0 = E[(size_t)(l * 4 + 0) * K_CODES + bi];
        const float q1 = E[(size_t)(l * 4 + 1) * K_CODES + bi];
        const float q2 = E[(size_t)(l * 4 + 2) * K_CODES + bi];
        const float q3 = E[(size_t)(l * 4 + 3) * K_CODES + bi];
        float4 q; q.x = q0; q.y = q1; q.z = q2; q.w = q3;
        *(float4*)(out + (size_t)row * DIM + l * 4) = q;
        const float d0 = x.x - q0, d1 = x.y - q1, d2 = x.z - q2, d3 = x.w - q3;
        lsum += d0 * d0 + d1 * d1 + d2 * d2 + d3 * d3;
    }
    // deterministic wave reduce
#pragma unroll
    for (int m = 32; m >= 1; m >>= 1) lsum += __shfl_xor(lsum, m, 64);
    __shared__ float ws4[4];
    if (l == 0) ws4[w] = lsum;
    __syncthreads();
    if (threadIdx.x == 0) partials[blockIdx.x] = (ws4[0] + ws4[1]) + (ws4[2] + ws4[3]);
}

__global__ void finalize(const float* __restrict__ partials, float* __restrict__ out_loss) {
    __shared__ double s[256];
    double a = 0.0;
    for (int i = threadIdx.x; i < GATHER_BLOCKS; i += 256) a += (double)partials[i];
    s[threadIdx.x] = a;
    __syncthreads();
    for (int st = 128; st > 0; st >>= 1) {
        if (threadIdx.x < st) s[threadIdx.x] += s[threadIdx.x + st];
        __syncthreads();
    }
    if (threadIdx.x == 0)
        out_loss[0] = (float)(1.25 * s[0] / (double)(N_ROWS * DIM));
}

extern "C" void kernel_launch(void* const* d_in, const int* in_sizes, int n_in,
                              void* d_out, int out_size, void* d_ws, size_t ws_size,
                              hipStream_t stream) {
    const float* X = (const float*)d_in[0];
    const float* E = (const float*)d_in[1];
    float* out = (float*)d_out;
    float* esq      = (float*)((char*)d_ws + WS_ESQ_OFF);
    float* candv    = (float*)((char*)d_ws + WS_CANDV_OFF);
    int*   candi    = (int*)  ((char*)d_ws + WS_CANDI_OFF);
    float* partials = (float*)((char*)d_ws + WS_PART_OFF);

    esq_kernel<<<K_CODES / 16, 256, 0, stream>>>(E, esq);
    dist_argmin<<<dim3(N_ROWS / BM, NKSLICE), 256, 0, stream>>>(X, E, esq, candv, candi);
    gather_loss<<<GATHER_BLOCKS, 256, 0, stream>>>(X, E, candv, candi, out, partials);
    finalize<<<1, 256, 0, stream>>>(partials, out + (size_t)N_ROWS * DIM);
}

// Round 3
// 895.790 us; speedup vs baseline: 1.6180x; 1.6180x over previous
//
#include <hip/hip_runtime.h>

// Vector Quantizer, MFMA split-bf16 path + exact fp32 refine.
// inputs  d_in[0]: float32 X [32768, 256]
// emb     d_in[1]: float32 E [256, 4096]
// d_out: [8388608 floats e_k] + [1 float loss]
//
// dot(x,e) ~ 3 bf16 MFMAs: xh*eh + xh*el + xl*eh (fp32 accum).
// bf16 path keeps top-2 candidates per (row, 512-col strip); refine kernel
// recomputes exact fp32 distances for the 16 candidates/row and picks argmin
// (first-index tie-break) -> immune to bf16-level distance noise.
// Xh/Xl bf16 are staged in d_out (exact fit, overwritten by gather later).

typedef unsigned short ushort_t;
typedef unsigned int uint_t;
typedef __attribute__((ext_vector_type(8))) short bf16x8;
typedef __attribute__((ext_vector_type(4))) float f32x4;

#define N_ROWS 32768
#define DIM 256
#define K_CODES 4096
#define NKS 8            // col strips (512 cols each)
#define GATHER_BLOCKS 512

// ---- ws layout (mfma path), bytes ----
// Ehi      [0,       2097152)   bf16 [4096][256]
// Elo      [2097152, 4194304)
// candi2   [4194304, 6291456)   int [32768][8 strips][2]
// esq      [6291456, 6307840)   float[4096]
// fidx     [6307840, 6438912)   int [32768]
// partials [6438912, 6440960)   float[512]
#define WS_NEEDED (8u * 1024u * 1024u)

__device__ __forceinline__ unsigned short bf16_rne(float x) {
    unsigned u = __builtin_bit_cast(unsigned, x);
    unsigned r = u + 0x7fffu + ((u >> 16) & 1u);
    return (unsigned short)(r >> 16);
}
__device__ __forceinline__ float bf16_f(unsigned short h) {
    unsigned u = ((unsigned)h) << 16;
    return __builtin_bit_cast(float, u);
}
// total-order "better": smaller dist, tie -> smaller index
__device__ __forceinline__ bool better(float d, int c, float v, int i) {
    return (d < v) || (d == v && c < i);
}

// ---------------- prep: X -> Xh/Xl (bf16 split), into d_out ----------------
__global__ void prep_x(const float* __restrict__ X, ushort_t* __restrict__ Xh,
                       ushort_t* __restrict__ Xl) {
    int i = blockIdx.x * 256 + threadIdx.x;   // float4 index
    float4 v = ((const float4*)X)[i];
    ushort4 h, l;
    h.x = bf16_rne(v.x); l.x = bf16_rne(v.x - bf16_f(h.x));
    h.y = bf16_rne(v.y); l.y = bf16_rne(v.y - bf16_f(h.y));
    h.z = bf16_rne(v.z); l.z = bf16_rne(v.z - bf16_f(h.z));
    h.w = bf16_rne(v.w); l.w = bf16_rne(v.w - bf16_f(h.w));
    ((ushort4*)Xh)[i] = h;
    ((ushort4*)Xl)[i] = l;
}

// ------------- prep: E [256][4096] -> E^T hi/lo [4096][256] bf16 -----------
__global__ void prep_e(const float* __restrict__ E, ushort_t* __restrict__ Ehi,
                       ushort_t* __restrict__ Elo) {
    __shared__ ushort_t sh[64][66];
    __shared__ ushort_t sl[64][66];
    const int t = threadIdx.x;
    const int kbase = blockIdx.x * 64;
    const int dbase = blockIdx.y * 64;
#pragma unroll
    for (int i = 0; i < 16; ++i) {
        int lin = i * 256 + t;
        int dl = lin >> 6, kl = lin & 63;
        float v = E[(size_t)(dbase + dl) * K_CODES + kbase + kl];
        unsigned short h = bf16_rne(v);
        unsigned short l = bf16_rne(v - bf16_f(h));
        sh[kl][dl] = h;
        sl[kl][dl] = l;
    }
    __syncthreads();
#pragma unroll
    for (int i = 0; i < 8; ++i) {
        int lin = i * 256 + t;
        int kl = lin >> 5, d2 = (lin & 31) * 2;
        uint_t vh = (uint_t)sh[kl][d2] | ((uint_t)sh[kl][d2 + 1] << 16);
        uint_t vl = (uint_t)sl[kl][d2] | ((uint_t)sl[kl][d2 + 1] << 16);
        *(uint_t*)&Ehi[(size_t)(kbase + kl) * DIM + dbase + d2] = vh;
        *(uint_t*)&Elo[(size_t)(kbase + kl) * DIM + dbase + d2] = vl;
    }
}

// ---------------- esq[k] = sum_d E[d][k]^2 (fp32, from original E) ---------
__global__ void esq_kernel(const float* __restrict__ E, float* __restrict__ esq) {
    __shared__ float red[16][17];
    int t = threadIdx.x;
    int kk = t & 15, dg = t >> 4;
    int k = blockIdx.x * 16 + kk;
    float a = 0.f;
#pragma unroll
    for (int it = 0; it < 16; ++it) {
        float e = E[(dg + it * 16) * K_CODES + k];
        a = fmaf(e, e, a);
    }
    red[dg][kk] = a;
    __syncthreads();
    if (t < 16) {
        float s = 0.f;
#pragma unroll
        for (int g = 0; g < 16; ++g) s += red[g][t];
        esq[blockIdx.x * 16 + t] = s;
    }
}

// ---------------- main: MFMA distance + per-strip top-2 --------------------
// grid (NKS strips, 256 row-blocks), 256 threads = 4 waves.
// Wave w owns rows [w*32, w*32+32) x ALL 128 cols of each col tile -> no
// cross-wave candidate race. Each wave stages A/B blocks {2w, 2w+1}.
// LDS (shorts): A_hi[0,4096) A_lo[4096,8192) B_hi[8192,12288) B_lo[12288,16384)
// each region = [8 blocks of 16][64 lanes][8 bf16]  (fragment-packed)
__global__ __launch_bounds__(256) void dist_mfma(
    const ushort_t* __restrict__ Xh, const ushort_t* __restrict__ Xl,
    const ushort_t* __restrict__ Ehi, const ushort_t* __restrict__ Elo,
    const float* __restrict__ esq, int* __restrict__ candi2) {
    __shared__ short lds[16384];   // 32 KB
    const int t = threadIdx.x;
    const int l = t & 63, w = t >> 6;
    const int l15 = l & 15, lg = l >> 4;
    const int ks = blockIdx.x;
    const int rowbase = blockIdx.y * 128;

    const int ab0 = 2 * w, ab1 = 2 * w + 1;   // staged blocks for this wave
    const size_t aoff0 = (size_t)(rowbase + ab0 * 16 + l15) * DIM + lg * 8;
    const size_t aoff1 = (size_t)(rowbase + ab1 * 16 + l15) * DIM + lg * 8;

    float v1[2][4], v2[2][4];
    int   i1[2][4], i2[2][4];
#pragma unroll
    for (int m = 0; m < 2; ++m)
#pragma unroll
        for (int q = 0; q < 4; ++q) {
            v1[m][q] = 3.4e38f; v2[m][q] = 3.4e38f;
            i1[m][q] = 0x7fffffff; i2[m][q] = 0x7fffffff;
        }

#pragma unroll 1
    for (int ct = 0; ct < 4; ++ct) {
        const int cb = ks * 512 + ct * 128;
        const size_t boff0 = (size_t)(cb + ab0 * 16 + l15) * DIM + lg * 8;
        const size_t boff1 = (size_t)(cb + ab1 * 16 + l15) * DIM + lg * 8;

        f32x4 acc[2][8];
#pragma unroll
        for (int m = 0; m < 2; ++m)
#pragma unroll
            for (int n = 0; n < 8; ++n) acc[m][n] = (f32x4){0.f, 0.f, 0.f, 0.f};

#pragma unroll 1
        for (int kt = 0; kt < 8; ++kt) {
            const int ko = kt * 32;
#define GLDS(srcp, dstoff)                                                      \
    __builtin_amdgcn_global_load_lds(                                           \
        (const __attribute__((address_space(1))) void*)(srcp),                  \
        (__attribute__((address_space(3))) void*)&lds[dstoff], 16, 0, 0)
            GLDS(Xh + aoff0 + ko, ab0 * 512);
            GLDS(Xh + aoff1 + ko, ab1 * 512);
            GLDS(Xl + aoff0 + ko, 4096 + ab0 * 512);
            GLDS(Xl + aoff1 + ko, 4096 + ab1 * 512);
            GLDS(Ehi + boff0 + ko, 8192 + ab0 * 512);
            GLDS(Ehi + boff1 + ko, 8192 + ab1 * 512);
            GLDS(Elo + boff0 + ko, 12288 + ab0 * 512);
            GLDS(Elo + boff1 + ko, 12288 + ab1 * 512);
#undef GLDS
            __syncthreads();

            bf16x8 ah[2], al[2];
#pragma unroll
            for (int m = 0; m < 2; ++m) {
                ah[m] = *(const bf16x8*)&lds[(2 * w + m) * 512 + l * 8];
                al[m] = *(const bf16x8*)&lds[4096 + (2 * w + m) * 512 + l * 8];
            }
#pragma unroll
            for (int n = 0; n < 8; ++n) {
                const bf16x8 bh = *(const bf16x8*)&lds[8192 + n * 512 + l * 8];
                const bf16x8 bl = *(const bf16x8*)&lds[12288 + n * 512 + l * 8];
#pragma unroll
                for (int m = 0; m < 2; ++m) {
                    acc[m][n] = __builtin_amdgcn_mfma_f32_16x16x32_bf16(
                        ah[m], bh, acc[m][n], 0, 0, 0);
                    acc[m][n] = __builtin_amdgcn_mfma_f32_16x16x32_bf16(
                        ah[m], bl, acc[m][n], 0, 0, 0);
                    acc[m][n] = __builtin_amdgcn_mfma_f32_16x16x32_bf16(
                        al[m], bh, acc[m][n], 0, 0, 0);
                }
            }
            __syncthreads();
        }

        // epilogue: dist = esq - 2*dot, top-2 update per (m,q)
#pragma unroll
        for (int n = 0; n < 8; ++n) {
            const int col = cb + n * 16 + l15;
            const float eq = esq[col];
#pragma unroll
            for (int m = 0; m < 2; ++m)
#pragma unroll
                for (int q = 0; q < 4; ++q) {
                    const float d = fmaf(-2.f, acc[m][n][q], eq);
                    if (better(d, col, v1[m][q], i1[m][q])) {
                        v2[m][q] = v1[m][q]; i2[m][q] = i1[m][q];
                        v1[m][q] = d;        i1[m][q] = col;
                    } else if (better(d, col, v2[m][q], i2[m][q])) {
                        v2[m][q] = d; i2[m][q] = col;
                    }
                }
        }
    }

    // cross-lane top-2 merge over the 16 col-lanes (indices all distinct)
#pragma unroll
    for (int m = 0; m < 2; ++m)
#pragma unroll
        for (int q = 0; q < 4; ++q) {
            float a1 = v1[m][q], a2 = v2[m][q];
            int   b1 = i1[m][q], b2 = i2[m][q];
#pragma unroll
            for (int msk = 8; msk >= 1; msk >>= 1) {
                const float c1 = __shfl_xor(a1, msk, 64);
                const int   d1 = __shfl_xor(b1, msk, 64);
                const float c2 = __shfl_xor(a2, msk, 64);
                const int   d2 = __shfl_xor(b2, msk, 64);
                if (better(c1, d1, a1, b1)) {
                    // partner's best wins; second = min(my best, partner's 2nd)
                    if (better(a1, b1, c2, d2)) { a2 = a1; b2 = b1; }
                    else                        { a2 = c2; b2 = d2; }
                    a1 = c1; b1 = d1;
                } else {
                    if (better(c1, d1, a2, b2)) { a2 = c1; b2 = d1; }
                }
            }
            if (l15 == 0) {
                const int row = rowbase + w * 32 + m * 16 + lg * 4 + q;
                candi2[(row * NKS + ks) * 2 + 0] = b1;
                candi2[(row * NKS + ks) * 2 + 1] = b2;
            }
        }
}

// -------- refine: exact fp32 distance over 16 candidates/row ---------------
// 1 wave per row: lane = (cand 0..15) x (dim-group 0..3 of 64 dims).
// dist(c) = sum_d E[d][c]*(E[d][c] - 2 x[d])   (row-constant ||x||^2 dropped)
__global__ void refine(const float* __restrict__ X, const float* __restrict__ E,
                       const int* __restrict__ cand, int* __restrict__ fidx) {
    const int w = threadIdx.x >> 6, l = threadIdx.x & 63;
    const int row = blockIdx.x * 4 + w;
    const int cs = l & 15, dg = l >> 4;
    const int c = cand[row * 16 + cs];
    float p = 0.f;
    const float* xp = X + (size_t)row * DIM + dg * 64;
    const float* ep = E + (size_t)(dg * 64) * K_CODES + c;
#pragma unroll 8
    for (int j = 0; j < 64; ++j) {
        const float e = ep[(size_t)j * K_CODES];
        p = fmaf(e, e - 2.f * xp[j], p);
    }
    p += __shfl_xor(p, 16, 64);
    p += __shfl_xor(p, 32, 64);
    float v = p; int id = c;
#pragma unroll
    for (int m = 8; m >= 1; m >>= 1) {
        const float v2 = __shfl_xor(v, m, 64);
        const int  id2 = __shfl_xor(id, m, 64);
        if (v2 < v || (v2 == v && id2 < id)) { v = v2; id = id2; }
    }
    if (l == 0) fidx[row] = id;
}

// ---------------- gather + loss partials (final idx) -----------------------
__global__ void gather_fidx(const float* __restrict__ X, const float* __restrict__ E,
                            const int* __restrict__ fidx,
                            float* __restrict__ out, float* __restrict__ partials) {
    const int w = threadIdx.x >> 6;
    const int l = threadIdx.x & 63;
    const int rowbase = blockIdx.x * (N_ROWS / GATHER_BLOCKS);  // 64 rows/block
    float lsum = 0.f;

    for (int rr = w; rr < N_ROWS / GATHER_BLOCKS; rr += 4) {
        const int row = rowbase + rr;
        const int bi = fidx[row];
        const float4 x = *(const float4*)(X + (size_t)row * DIM + l * 4);
        const float q0 = E[(size_t)(l * 4 + 0) * K_CODES + bi];
        const float q1 = E[(size_t)(l * 4 + 1) * K_CODES + bi];
        const float q2 = E[(size_t)(l * 4 + 2) * K_CODES + bi];
        const float q3 = E[(size_t)(l * 4 + 3) * K_CODES + bi];
        float4 q; q.x = q0; q.y = q1; q.z = q2; q.w = q3;
        *(float4*)(out + (size_t)row * DIM + l * 4) = q;
        const float d0 = x.x - q0, d1 = x.y - q1, d2 = x.z - q2, d3 = x.w - q3;
        lsum += d0 * d0 + d1 * d1 + d2 * d2 + d3 * d3;
    }
#pragma unroll
    for (int m = 32; m >= 1; m >>= 1) lsum += __shfl_xor(lsum, m, 64);
    __shared__ float ws4[4];
    if (l == 0) ws4[w] = lsum;
    __syncthreads();
    if (threadIdx.x == 0) partials[blockIdx.x] = (ws4[0] + ws4[1]) + (ws4[2] + ws4[3]);
}

// -------- fallback fp32 dist (round-1 proven path, used if ws too small) ---
__global__ void dist_fp32(const float* __restrict__ X, const float* __restrict__ E,
                          const float* __restrict__ esq,
                          float* __restrict__ candv, int* __restrict__ candi) {
    __shared__ float Xs[8][128];
    __shared__ float Es[8][128];
    const int t = threadIdx.x;
    const int tx = t & 15;
    const int ty = t >> 4;
    const int rowbase = blockIdx.x * 128;
    const int ks = blockIdx.y;

    float minv[8];
    int   mini[8];
#pragma unroll
    for (int i = 0; i < 8; ++i) { minv[i] = 3.4e38f; mini[i] = 0; }

    for (int kt = 0; kt < 8; ++kt) {
        const int kbase = ks * 1024 + kt * 128;
        float acc[8][8];
#pragma unroll
        for (int i = 0; i < 8; ++i)
#pragma unroll
            for (int j = 0; j < 8; ++j) acc[i][j] = 0.f;

        for (int dc = 0; dc < DIM / 8; ++dc) {
            const int d0 = dc * 8;
            {
                const int row = t >> 1;
                const int dsl = (t & 1) * 4;
                const float4 xv = *(const float4*)(X + (size_t)(rowbase + row) * DIM + d0 + dsl);
                Xs[dsl + 0][row] = xv.x; Xs[dsl + 1][row] = xv.y;
                Xs[dsl + 2][row] = xv.z; Xs[dsl + 3][row] = xv.w;
            }
            {
                const int dr = t >> 5;
                const int c4 = (t & 31) * 4;
                const float4 ev = *(const float4*)(E + (size_t)(d0 + dr) * K_CODES + kbase + c4);
                *(float4*)&Es[dr][c4] = ev;
            }
            __syncthreads();
#pragma unroll
            for (int d = 0; d < 8; ++d) {
                float xr[8], er[8];
                *(float4*)&xr[0] = *(const float4*)&Xs[d][ty * 8];
                *(float4*)&xr[4] = *(const float4*)&Xs[d][ty * 8 + 4];
                *(float4*)&er[0] = *(const float4*)&Es[d][tx * 8];
                *(float4*)&er[4] = *(const float4*)&Es[d][tx * 8 + 4];
#pragma unroll
                for (int i = 0; i < 8; ++i)
#pragma unroll
                    for (int j = 0; j < 8; ++j)
                        acc[i][j] = fmaf(xr[i], er[j], acc[i][j]);
            }
            __syncthreads();
        }
        float eq[8];
        *(float4*)&eq[0] = *(const float4*)(esq + kbase + tx * 8);
        *(float4*)&eq[4] = *(const float4*)(esq + kbase + tx * 8 + 4);
#pragma unroll
        for (int i = 0; i < 8; ++i)
#pragma unroll
            for (int j = 0; j < 8; ++j) {
                const float dist = fmaf(-2.f, acc[i][j], eq[j]);
                if (dist < minv[i]) { minv[i] = dist; mini[i] = kbase + tx * 8 + j; }
            }
    }
#pragma unroll
    for (int i = 0; i < 8; ++i) {
        float v = minv[i];
        int   id = mini[i];
#pragma unroll
        for (int m = 8; m >= 1; m >>= 1) {
            const float v2 = __shfl_xor(v, m, 64);
            const int   i2 = __shfl_xor(id, m, 64);
            if (v2 < v || (v2 == v && i2 < id)) { v = v2; id = i2; }
        }
        if (tx == 0) {
            const int row = rowbase + ty * 8 + i;
            candv[row * 4 + ks] = v;
            candi[row * 4 + ks] = id;
        }
    }
}

__global__ void gather_loss(const float* __restrict__ X, const float* __restrict__ E,
                            const float* __restrict__ candv, const int* __restrict__ candi,
                            float* __restrict__ out, float* __restrict__ partials,
                            int nks) {
    const int w = threadIdx.x >> 6;
    const int l = threadIdx.x & 63;
    const int rowbase = blockIdx.x * (N_ROWS / GATHER_BLOCKS);
    float lsum = 0.f;

    for (int rr = w; rr < N_ROWS / GATHER_BLOCKS; rr += 4) {
        const int row = rowbase + rr;
        float bv = candv[row * nks];
        int   bi = candi[row * nks];
        for (int s = 1; s < nks; ++s) {
            const float v = candv[row * nks + s];
            const int  id = candi[row * nks + s];
            if (v < bv || (v == bv && id < bi)) { bv = v; bi = id; }
        }
        const float4 x = *(const float4*)(X + (size_t)row * DIM + l * 4);
        const float q0 = E[(size_t)(l * 4 + 0) * K_CODES + bi];
        const float q1 = E[(size_t)(l * 4 + 1) * K_CODES + bi];
        const float q2 = E[(size_t)(l * 4 + 2) * K_CODES + bi];
        const float q3 = E[(size_t)(l * 4 + 3) * K_CODES + bi];
        float4 q; q.x = q0; q.y = q1; q.z = q2; q.w = q3;
        *(float4*)(out + (size_t)row * DIM + l * 4) = q;
        const float d0 = x.x - q0, d1 = x.y - q1, d2 = x.z - q2, d3 = x.w - q3;
        lsum += d0 * d0 + d1 * d1 + d2 * d2 + d3 * d3;
    }
#pragma unroll
    for (int m = 32; m >= 1; m >>= 1) lsum += __shfl_xor(lsum, m, 64);
    __shared__ float ws4[4];
    if (l == 0) ws4[w] = lsum;
    __syncthreads();
    if (threadIdx.x == 0) partials[blockIdx.x] = (ws4[0] + ws4[1]) + (ws4[2] + ws4[3]);
}

__global__ void finalize(const float* __restrict__ partials, float* __restrict__ out_loss) {
    __shared__ double s[256];
    double a = 0.0;
    for (int i = threadIdx.x; i < GATHER_BLOCKS; i += 256) a += (double)partials[i];
    s[threadIdx.x] = a;
    __syncthreads();
    for (int st = 128; st > 0; st >>= 1) {
        if (threadIdx.x < st) s[threadIdx.x] += s[threadIdx.x + st];
        __syncthreads();
    }
    if (threadIdx.x == 0)
        out_loss[0] = (float)(1.25 * s[0] / (double)(N_ROWS * DIM));
}

extern "C" void kernel_launch(void* const* d_in, const int* in_sizes, int n_in,
                              void* d_out, int out_size, void* d_ws, size_t ws_size,
                              hipStream_t stream) {
    const float* X = (const float*)d_in[0];
    const float* E = (const float*)d_in[1];
    float* out = (float*)d_out;

    if (ws_size >= (size_t)WS_NEEDED) {
        // ---------------- MFMA path ----------------
        ushort_t* Ehi      = (ushort_t*)((char*)d_ws + 0);
        ushort_t* Elo      = (ushort_t*)((char*)d_ws + 2097152);
        int*      candi2   = (int*)     ((char*)d_ws + 4194304);
        float*    esq      = (float*)   ((char*)d_ws + 6291456);
        int*      fidx     = (int*)     ((char*)d_ws + 6307840);
        float*    partials = (float*)   ((char*)d_ws + 6438912);
        ushort_t* Xh       = (ushort_t*)d_out;                  // 16.78 MB
        ushort_t* Xl       = Xh + (size_t)N_ROWS * DIM;         // 16.78 MB

        prep_x<<<(N_ROWS * DIM / 4) / 256, 256, 0, stream>>>(X, Xh, Xl);
        prep_e<<<dim3(K_CODES / 64, DIM / 64), 256, 0, stream>>>(E, Ehi, Elo);
        esq_kernel<<<K_CODES / 16, 256, 0, stream>>>(E, esq);
        dist_mfma<<<dim3(NKS, N_ROWS / 128), 256, 0, stream>>>(
            Xh, Xl, Ehi, Elo, esq, candi2);
        refine<<<N_ROWS / 4, 256, 0, stream>>>(X, E, candi2, fidx);
        gather_fidx<<<GATHER_BLOCKS, 256, 0, stream>>>(X, E, fidx, out, partials);
        finalize<<<1, 256, 0, stream>>>(partials, out + (size_t)N_ROWS * DIM);
    } else {
        // ---------------- fallback: round-1 fp32 path (needs ~1.07 MB) -----
        float* esq      = (float*)((char*)d_ws + 0);
        float* candv    = (float*)((char*)d_ws + 16384);
        int*   candi    = (int*)  ((char*)d_ws + 540672);
        float* partials = (float*)((char*)d_ws + 1064960);

        esq_kernel<<<K_CODES / 16, 256, 0, stream>>>(E, esq);
        dist_fp32<<<dim3(N_ROWS / 128, 4), 256, 0, stream>>>(X, E, esq, candv, candi);
        gather_loss<<<GATHER_BLOCKS, 256, 0, stream>>>(X, E, candv, candi, out,
                                                       partials, 4);
        finalize<<<1, 256, 0, stream>>>(partials, out + (size_t)N_ROWS * DIM);
    }
}

// Round 4
// 481.177 us; speedup vs baseline: 3.0122x; 1.8617x over previous
//
#include <hip/hip_runtime.h>

// Vector Quantizer, MFMA split-bf16 path + exact fp32 refine (row-major Et).
// inputs  d_in[0]: float32 X [32768, 256]
// emb     d_in[1]: float32 E [256, 4096]
// d_out: [8388608 floats e_k] + [1 float loss]
//
// dot(x,e) ~ 3 bf16 MFMAs: xh*eh + xh*el + xl*eh (fp32 accum).
// bf16 path keeps top-2 candidates per (row, 512-col strip); refine kernel
// recomputes exact fp32 distances for the 16 candidates/row from a row-major
// fp32 transpose Et[4096][256] (contiguous reads) and picks argmin.
// Et is built AFTER dist_mfma, overwriting the dead Ehi/Elo ws region.
// Xh/Xl bf16 are staged in d_out (exact fit, overwritten by gather later).

typedef unsigned short ushort_t;
typedef unsigned int uint_t;
typedef __attribute__((ext_vector_type(8))) short bf16x8;
typedef __attribute__((ext_vector_type(4))) float f32x4;

#define N_ROWS 32768
#define DIM 256
#define K_CODES 4096
#define NKS 8            // col strips (512 cols each)
#define GATHER_BLOCKS 512

// ---- ws layout (mfma path), bytes ----
// Ehi      [0,       2097152)   bf16 [4096][256]   (dead after dist_mfma)
// Elo      [2097152, 4194304)                      (dead after dist_mfma)
// Et       [0,       4194304)   fp32 [4096][256]   (built after dist_mfma)
// candi2   [4194304, 6291456)   int [32768][8 strips][2]
// esq      [6291456, 6307840)   float[4096]
// fidx     [6307840, 6438912)   int [32768]
// partials [6438912, 6440960)   float[512]
#define WS_NEEDED (8u * 1024u * 1024u)

__device__ __forceinline__ unsigned short bf16_rne(float x) {
    unsigned u = __builtin_bit_cast(unsigned, x);
    unsigned r = u + 0x7fffu + ((u >> 16) & 1u);
    return (unsigned short)(r >> 16);
}
__device__ __forceinline__ float bf16_f(unsigned short h) {
    unsigned u = ((unsigned)h) << 16;
    return __builtin_bit_cast(float, u);
}
// total-order "better": smaller dist, tie -> smaller index
__device__ __forceinline__ bool better(float d, int c, float v, int i) {
    return (d < v) || (d == v && c < i);
}

// ---------------- prep: X -> Xh/Xl (bf16 split), into d_out ----------------
__global__ void prep_x(const float* __restrict__ X, ushort_t* __restrict__ Xh,
                       ushort_t* __restrict__ Xl) {
    int i = blockIdx.x * 256 + threadIdx.x;   // float4 index
    float4 v = ((const float4*)X)[i];
    ushort4 h, l;
    h.x = bf16_rne(v.x); l.x = bf16_rne(v.x - bf16_f(h.x));
    h.y = bf16_rne(v.y); l.y = bf16_rne(v.y - bf16_f(h.y));
    h.z = bf16_rne(v.z); l.z = bf16_rne(v.z - bf16_f(h.z));
    h.w = bf16_rne(v.w); l.w = bf16_rne(v.w - bf16_f(h.w));
    ((ushort4*)Xh)[i] = h;
    ((ushort4*)Xl)[i] = l;
}

// ------------- prep: E [256][4096] -> E^T hi/lo [4096][256] bf16 -----------
__global__ void prep_e(const float* __restrict__ E, ushort_t* __restrict__ Ehi,
                       ushort_t* __restrict__ Elo) {
    __shared__ ushort_t sh[64][66];
    __shared__ ushort_t sl[64][66];
    const int t = threadIdx.x;
    const int kbase = blockIdx.x * 64;
    const int dbase = blockIdx.y * 64;
#pragma unroll
    for (int i = 0; i < 16; ++i) {
        int lin = i * 256 + t;
        int dl = lin >> 6, kl = lin & 63;
        float v = E[(size_t)(dbase + dl) * K_CODES + kbase + kl];
        unsigned short h = bf16_rne(v);
        unsigned short l = bf16_rne(v - bf16_f(h));
        sh[kl][dl] = h;
        sl[kl][dl] = l;
    }
    __syncthreads();
#pragma unroll
    for (int i = 0; i < 8; ++i) {
        int lin = i * 256 + t;
        int kl = lin >> 5, d2 = (lin & 31) * 2;
        uint_t vh = (uint_t)sh[kl][d2] | ((uint_t)sh[kl][d2 + 1] << 16);
        uint_t vl = (uint_t)sl[kl][d2] | ((uint_t)sl[kl][d2 + 1] << 16);
        *(uint_t*)&Ehi[(size_t)(kbase + kl) * DIM + dbase + d2] = vh;
        *(uint_t*)&Elo[(size_t)(kbase + kl) * DIM + dbase + d2] = vl;
    }
}

// ------------- prep: E [256][4096] -> Et fp32 [4096][256] (exact) ----------
__global__ void prep_et(const float* __restrict__ E, float* __restrict__ Et) {
    __shared__ float s[64][65];
    const int t = threadIdx.x;
    const int kbase = blockIdx.x * 64;
    const int dbase = blockIdx.y * 64;
#pragma unroll
    for (int i = 0; i < 16; ++i) {
        int lin = i * 256 + t;
        int dl = lin >> 6, kl = lin & 63;
        s[kl][dl] = E[(size_t)(dbase + dl) * K_CODES + kbase + kl];
    }
    __syncthreads();
#pragma unroll
    for (int i = 0; i < 16; ++i) {
        int lin = i * 256 + t;
        int kl = lin >> 6, dl = lin & 63;
        Et[(size_t)(kbase + kl) * DIM + dbase + dl] = s[kl][dl];
    }
}

// ---------------- esq[k] = sum_d E[d][k]^2 (fp32, from original E) ---------
__global__ void esq_kernel(const float* __restrict__ E, float* __restrict__ esq) {
    __shared__ float red[16][17];
    int t = threadIdx.x;
    int kk = t & 15, dg = t >> 4;
    int k = blockIdx.x * 16 + kk;
    float a = 0.f;
#pragma unroll
    for (int it = 0; it < 16; ++it) {
        float e = E[(dg + it * 16) * K_CODES + k];
        a = fmaf(e, e, a);
    }
    red[dg][kk] = a;
    __syncthreads();
    if (t < 16) {
        float s = 0.f;
#pragma unroll
        for (int g = 0; g < 16; ++g) s += red[g][t];
        esq[blockIdx.x * 16 + t] = s;
    }
}

// ---------------- main: MFMA distance + per-strip top-2 --------------------
// grid (NKS strips, 256 row-blocks), 256 threads = 4 waves.
// Wave w owns rows [w*32, w*32+32) x ALL 128 cols of each col tile -> no
// cross-wave candidate race. Each wave stages A/B blocks {2w, 2w+1}.
// LDS (shorts): A_hi[0,4096) A_lo[4096,8192) B_hi[8192,12288) B_lo[12288,16384)
// each region = [8 blocks of 16][64 lanes][8 bf16]  (fragment-packed)
__global__ __launch_bounds__(256) void dist_mfma(
    const ushort_t* __restrict__ Xh, const ushort_t* __restrict__ Xl,
    const ushort_t* __restrict__ Ehi, const ushort_t* __restrict__ Elo,
    const float* __restrict__ esq, int* __restrict__ candi2) {
    __shared__ short lds[16384];   // 32 KB
    const int t = threadIdx.x;
    const int l = t & 63, w = t >> 6;
    const int l15 = l & 15, lg = l >> 4;
    const int ks = blockIdx.x;
    const int rowbase = blockIdx.y * 128;

    const int ab0 = 2 * w, ab1 = 2 * w + 1;   // staged blocks for this wave
    const size_t aoff0 = (size_t)(rowbase + ab0 * 16 + l15) * DIM + lg * 8;
    const size_t aoff1 = (size_t)(rowbase + ab1 * 16 + l15) * DIM + lg * 8;

    float v1[2][4], v2[2][4];
    int   i1[2][4], i2[2][4];
#pragma unroll
    for (int m = 0; m < 2; ++m)
#pragma unroll
        for (int q = 0; q < 4; ++q) {
            v1[m][q] = 3.4e38f; v2[m][q] = 3.4e38f;
            i1[m][q] = 0x7fffffff; i2[m][q] = 0x7fffffff;
        }

#pragma unroll 1
    for (int ct = 0; ct < 4; ++ct) {
        const int cb = ks * 512 + ct * 128;
        const size_t boff0 = (size_t)(cb + ab0 * 16 + l15) * DIM + lg * 8;
        const size_t boff1 = (size_t)(cb + ab1 * 16 + l15) * DIM + lg * 8;

        f32x4 acc[2][8];
#pragma unroll
        for (int m = 0; m < 2; ++m)
#pragma unroll
            for (int n = 0; n < 8; ++n) acc[m][n] = (f32x4){0.f, 0.f, 0.f, 0.f};

#pragma unroll 1
        for (int kt = 0; kt < 8; ++kt) {
            const int ko = kt * 32;
#define GLDS(srcp, dstoff)                                                      \
    __builtin_amdgcn_global_load_lds(                                           \
        (const __attribute__((address_space(1))) void*)(srcp),                  \
        (__attribute__((address_space(3))) void*)&lds[dstoff], 16, 0, 0)
            GLDS(Xh + aoff0 + ko, ab0 * 512);
            GLDS(Xh + aoff1 + ko, ab1 * 512);
            GLDS(Xl + aoff0 + ko, 4096 + ab0 * 512);
            GLDS(Xl + aoff1 + ko, 4096 + ab1 * 512);
            GLDS(Ehi + boff0 + ko, 8192 + ab0 * 512);
            GLDS(Ehi + boff1 + ko, 8192 + ab1 * 512);
            GLDS(Elo + boff0 + ko, 12288 + ab0 * 512);
            GLDS(Elo + boff1 + ko, 12288 + ab1 * 512);
#undef GLDS
            __syncthreads();

            bf16x8 ah[2], al[2];
#pragma unroll
            for (int m = 0; m < 2; ++m) {
                ah[m] = *(const bf16x8*)&lds[(2 * w + m) * 512 + l * 8];
                al[m] = *(const bf16x8*)&lds[4096 + (2 * w + m) * 512 + l * 8];
            }
#pragma unroll
            for (int n = 0; n < 8; ++n) {
                const bf16x8 bh = *(const bf16x8*)&lds[8192 + n * 512 + l * 8];
                const bf16x8 bl = *(const bf16x8*)&lds[12288 + n * 512 + l * 8];
#pragma unroll
                for (int m = 0; m < 2; ++m) {
                    acc[m][n] = __builtin_amdgcn_mfma_f32_16x16x32_bf16(
                        ah[m], bh, acc[m][n], 0, 0, 0);
                    acc[m][n] = __builtin_amdgcn_mfma_f32_16x16x32_bf16(
                        ah[m], bl, acc[m][n], 0, 0, 0);
                    acc[m][n] = __builtin_amdgcn_mfma_f32_16x16x32_bf16(
                        al[m], bh, acc[m][n], 0, 0, 0);
                }
            }
            __syncthreads();
        }

        // epilogue: dist = esq - 2*dot, top-2 update per (m,q)
#pragma unroll
        for (int n = 0; n < 8; ++n) {
            const int col = cb + n * 16 + l15;
            const float eq = esq[col];
#pragma unroll
            for (int m = 0; m < 2; ++m)
#pragma unroll
                for (int q = 0; q < 4; ++q) {
                    const float d = fmaf(-2.f, acc[m][n][q], eq);
                    if (better(d, col, v1[m][q], i1[m][q])) {
                        v2[m][q] = v1[m][q]; i2[m][q] = i1[m][q];
                        v1[m][q] = d;        i1[m][q] = col;
                    } else if (better(d, col, v2[m][q], i2[m][q])) {
                        v2[m][q] = d; i2[m][q] = col;
                    }
                }
        }
    }

    // cross-lane top-2 merge over the 16 col-lanes (indices all distinct)
#pragma unroll
    for (int m = 0; m < 2; ++m)
#pragma unroll
        for (int q = 0; q < 4; ++q) {
            float a1 = v1[m][q], a2 = v2[m][q];
            int   b1 = i1[m][q], b2 = i2[m][q];
#pragma unroll
            for (int msk = 8; msk >= 1; msk >>= 1) {
                const float c1 = __shfl_xor(a1, msk, 64);
                const int   d1 = __shfl_xor(b1, msk, 64);
                const float c2 = __shfl_xor(a2, msk, 64);
                const int   d2 = __shfl_xor(b2, msk, 64);
                if (better(c1, d1, a1, b1)) {
                    if (better(a1, b1, c2, d2)) { a2 = a1; b2 = b1; }
                    else                        { a2 = c2; b2 = d2; }
                    a1 = c1; b1 = d1;
                } else {
                    if (better(c1, d1, a2, b2)) { a2 = c1; b2 = d1; }
                }
            }
            if (l15 == 0) {
                const int row = rowbase + w * 32 + m * 16 + lg * 4 + q;
                candi2[(row * NKS + ks) * 2 + 0] = b1;
                candi2[(row * NKS + ks) * 2 + 1] = b2;
            }
        }
}

// -------- refine: exact fp32 distance over 16 candidates/row ---------------
// 1 wave per row: lane = (cand 0..15) x (dim-group 0..3 of 64 dims).
// dist(c) = sum_d Et[c][d]*(Et[c][d] - 2 x[d])  -- contiguous float4 reads.
__global__ void refine(const float* __restrict__ X, const float* __restrict__ Et,
                       const int* __restrict__ cand, int* __restrict__ fidx) {
    const int w = threadIdx.x >> 6, l = threadIdx.x & 63;
    const int row = blockIdx.x * 4 + w;
    const int cs = l & 15, dg = l >> 4;
    const int c = cand[row * 16 + cs];
    const float4* ep = (const float4*)(Et + (size_t)c * DIM + dg * 64);
    const float4* xp = (const float4*)(X + (size_t)row * DIM + dg * 64);
    float p = 0.f;
#pragma unroll
    for (int j = 0; j < 16; ++j) {
        const float4 e = ep[j];
        const float4 x = xp[j];
        p = fmaf(e.x, fmaf(-2.f, x.x, e.x), p);
        p = fmaf(e.y, fmaf(-2.f, x.y, e.y), p);
        p = fmaf(e.z, fmaf(-2.f, x.z, e.z), p);
        p = fmaf(e.w, fmaf(-2.f, x.w, e.w), p);
    }
    p += __shfl_xor(p, 16, 64);
    p += __shfl_xor(p, 32, 64);
    float v = p; int id = c;
#pragma unroll
    for (int m = 8; m >= 1; m >>= 1) {
        const float v2 = __shfl_xor(v, m, 64);
        const int  id2 = __shfl_xor(id, m, 64);
        if (v2 < v || (v2 == v && id2 < id)) { v = v2; id = id2; }
    }
    if (l == 0) fidx[row] = id;
}

// ---------------- gather + loss partials (final idx, row-major Et) ---------
__global__ void gather_fidx(const float* __restrict__ X, const float* __restrict__ Et,
                            const int* __restrict__ fidx,
                            float* __restrict__ out, float* __restrict__ partials) {
    const int w = threadIdx.x >> 6;
    const int l = threadIdx.x & 63;
    const int rowbase = blockIdx.x * (N_ROWS / GATHER_BLOCKS);  // 64 rows/block
    float lsum = 0.f;

    for (int rr = w; rr < N_ROWS / GATHER_BLOCKS; rr += 4) {
        const int row = rowbase + rr;
        const int bi = fidx[row];
        const float4 x = *(const float4*)(X + (size_t)row * DIM + l * 4);
        const float4 q = *(const float4*)(Et + (size_t)bi * DIM + l * 4);
        *(float4*)(out + (size_t)row * DIM + l * 4) = q;
        const float d0 = x.x - q.x, d1 = x.y - q.y, d2 = x.z - q.z, d3 = x.w - q.w;
        lsum += d0 * d0 + d1 * d1 + d2 * d2 + d3 * d3;
    }
#pragma unroll
    for (int m = 32; m >= 1; m >>= 1) lsum += __shfl_xor(lsum, m, 64);
    __shared__ float ws4[4];
    if (l == 0) ws4[w] = lsum;
    __syncthreads();
    if (threadIdx.x == 0) partials[blockIdx.x] = (ws4[0] + ws4[1]) + (ws4[2] + ws4[3]);
}

// -------- fallback fp32 dist (round-1 proven path, used if ws too small) ---
__global__ void dist_fp32(const float* __restrict__ X, const float* __restrict__ E,
                          const float* __restrict__ esq,
                          float* __restrict__ candv, int* __restrict__ candi) {
    __shared__ float Xs[8][128];
    __shared__ float Es[8][128];
    const int t = threadIdx.x;
    const int tx = t & 15;
    const int ty = t >> 4;
    const int rowbase = blockIdx.x * 128;
    const int ks = blockIdx.y;

    float minv[8];
    int   mini[8];
#pragma unroll
    for (int i = 0; i < 8; ++i) { minv[i] = 3.4e38f; mini[i] = 0; }

    for (int kt = 0; kt < 8; ++kt) {
        const int kbase = ks * 1024 + kt * 128;
        float acc[8][8];
#pragma unroll
        for (int i = 0; i < 8; ++i)
#pragma unroll
            for (int j = 0; j < 8; ++j) acc[i][j] = 0.f;

        for (int dc = 0; dc < DIM / 8; ++dc) {
            const int d0 = dc * 8;
            {
                const int row = t >> 1;
                const int dsl = (t & 1) * 4;
                const float4 xv = *(const float4*)(X + (size_t)(rowbase + row) * DIM + d0 + dsl);
                Xs[dsl + 0][row] = xv.x; Xs[dsl + 1][row] = xv.y;
                Xs[dsl + 2][row] = xv.z; Xs[dsl + 3][row] = xv.w;
            }
            {
                const int dr = t >> 5;
                const int c4 = (t & 31) * 4;
                const float4 ev = *(const float4*)(E + (size_t)(d0 + dr) * K_CODES + kbase + c4);
                *(float4*)&Es[dr][c4] = ev;
            }
            __syncthreads();
#pragma unroll
            for (int d = 0; d < 8; ++d) {
                float xr[8], er[8];
                *(float4*)&xr[0] = *(const float4*)&Xs[d][ty * 8];
                *(float4*)&xr[4] = *(const float4*)&Xs[d][ty * 8 + 4];
                *(float4*)&er[0] = *(const float4*)&Es[d][tx * 8];
                *(float4*)&er[4] = *(const float4*)&Es[d][tx * 8 + 4];
#pragma unroll
                for (int i = 0; i < 8; ++i)
#pragma unroll
                    for (int j = 0; j < 8; ++j)
                        acc[i][j] = fmaf(xr[i], er[j], acc[i][j]);
            }
            __syncthreads();
        }
        float eq[8];
        *(float4*)&eq[0] = *(const float4*)(esq + kbase + tx * 8);
        *(float4*)&eq[4] = *(const float4*)(esq + kbase + tx * 8 + 4);
#pragma unroll
        for (int i = 0; i < 8; ++i)
#pragma unroll
            for (int j = 0; j < 8; ++j) {
                const float dist = fmaf(-2.f, acc[i][j], eq[j]);
                if (dist < minv[i]) { minv[i] = dist; mini[i] = kbase + tx * 8 + j; }
            }
    }
#pragma unroll
    for (int i = 0; i < 8; ++i) {
        float v = minv[i];
        int   id = mini[i];
#pragma unroll
        for (int m = 8; m >= 1; m >>= 1) {
            const float v2 = __shfl_xor(v, m, 64);
            const int   i2 = __shfl_xor(id, m, 64);
            if (v2 < v || (v2 == v && i2 < id)) { v = v2; id = i2; }
        }
        if (tx == 0) {
            const int row = rowbase + ty * 8 + i;
            candv[row * 4 + ks] = v;
            candi[row * 4 + ks] = id;
        }
    }
}

__global__ void gather_loss(const float* __restrict__ X, const float* __restrict__ E,
                            const float* __restrict__ candv, const int* __restrict__ candi,
                            float* __restrict__ out, float* __restrict__ partials,
                            int nks) {
    const int w = threadIdx.x >> 6;
    const int l = threadIdx.x & 63;
    const int rowbase = blockIdx.x * (N_ROWS / GATHER_BLOCKS);
    float lsum = 0.f;

    for (int rr = w; rr < N_ROWS / GATHER_BLOCKS; rr += 4) {
        const int row = rowbase + rr;
        float bv = candv[row * nks];
        int   bi = candi[row * nks];
        for (int s = 1; s < nks; ++s) {
            const float v = candv[row * nks + s];
            const int  id = candi[row * nks + s];
            if (v < bv || (v == bv && id < bi)) { bv = v; bi = id; }
        }
        const float4 x = *(const float4*)(X + (size_t)row * DIM + l * 4);
        const float q0 = E[(size_t)(l * 4 + 0) * K_CODES + bi];
        const float q1 = E[(size_t)(l * 4 + 1) * K_CODES + bi];
        const float q2 = E[(size_t)(l * 4 + 2) * K_CODES + bi];
        const float q3 = E[(size_t)(l * 4 + 3) * K_CODES + bi];
        float4 q; q.x = q0; q.y = q1; q.z = q2; q.w = q3;
        *(float4*)(out + (size_t)row * DIM + l * 4) = q;
        const float d0 = x.x - q0, d1 = x.y - q1, d2 = x.z - q2, d3 = x.w - q3;
        lsum += d0 * d0 + d1 * d1 + d2 * d2 + d3 * d3;
    }
#pragma unroll
    for (int m = 32; m >= 1; m >>= 1) lsum += __shfl_xor(lsum, m, 64);
    __shared__ float ws4[4];
    if (l == 0) ws4[w] = lsum;
    __syncthreads();
    if (threadIdx.x == 0) partials[blockIdx.x] = (ws4[0] + ws4[1]) + (ws4[2] + ws4[3]);
}

__global__ void finalize(const float* __restrict__ partials, float* __restrict__ out_loss) {
    __shared__ double s[256];
    double a = 0.0;
    for (int i = threadIdx.x; i < GATHER_BLOCKS; i += 256) a += (double)partials[i];
    s[threadIdx.x] = a;
    __syncthreads();
    for (int st = 128; st > 0; st >>= 1) {
        if (threadIdx.x < st) s[threadIdx.x] += s[threadIdx.x + st];
        __syncthreads();
    }
    if (threadIdx.x == 0)
        out_loss[0] = (float)(1.25 * s[0] / (double)(N_ROWS * DIM));
}

extern "C" void kernel_launch(void* const* d_in, const int* in_sizes, int n_in,
                              void* d_out, int out_size, void* d_ws, size_t ws_size,
                              hipStream_t stream) {
    const float* X = (const float*)d_in[0];
    const float* E = (const float*)d_in[1];
    float* out = (float*)d_out;

    if (ws_size >= (size_t)WS_NEEDED) {
        // ---------------- MFMA path ----------------
        ushort_t* Ehi      = (ushort_t*)((char*)d_ws + 0);
        ushort_t* Elo      = (ushort_t*)((char*)d_ws + 2097152);
        float*    Et       = (float*)   ((char*)d_ws + 0);        // after dist_mfma
        int*      candi2   = (int*)     ((char*)d_ws + 4194304);
        float*    esq      = (float*)   ((char*)d_ws + 6291456);
        int*      fidx     = (int*)     ((char*)d_ws + 6307840);
        float*    partials = (float*)   ((char*)d_ws + 6438912);
        ushort_t* Xh       = (ushort_t*)d_out;                    // 16.78 MB
        ushort_t* Xl       = Xh + (size_t)N_ROWS * DIM;           // 16.78 MB

        prep_x<<<(N_ROWS * DIM / 4) / 256, 256, 0, stream>>>(X, Xh, Xl);
        prep_e<<<dim3(K_CODES / 64, DIM / 64), 256, 0, stream>>>(E, Ehi, Elo);
        esq_kernel<<<K_CODES / 16, 256, 0, stream>>>(E, esq);
        dist_mfma<<<dim3(NKS, N_ROWS / 128), 256, 0, stream>>>(
            Xh, Xl, Ehi, Elo, esq, candi2);
        prep_et<<<dim3(K_CODES / 64, DIM / 64), 256, 0, stream>>>(E, Et);
        refine<<<N_ROWS / 4, 256, 0, stream>>>(X, Et, candi2, fidx);
        gather_fidx<<<GATHER_BLOCKS, 256, 0, stream>>>(X, Et, fidx, out, partials);
        finalize<<<1, 256, 0, stream>>>(partials, out + (size_t)N_ROWS * DIM);
    } else {
        // ---------------- fallback: round-1 fp32 path (needs ~1.07 MB) -----
        float* esq      = (float*)((char*)d_ws + 0);
        float* candv    = (float*)((char*)d_ws + 16384);
        int*   candi    = (int*)  ((char*)d_ws + 540672);
        float* partials = (float*)((char*)d_ws + 1064960);

        esq_kernel<<<K_CODES / 16, 256, 0, stream>>>(E, esq);
        dist_fp32<<<dim3(N_ROWS / 128, 4), 256, 0, stream>>>(X, E, esq, candv, candi);
        gather_loss<<<GATHER_BLOCKS, 256, 0, stream>>>(X, E, candv, candi, out,
                                                       partials, 4);
        finalize<<<1, 256, 0, stream>>>(partials, out + (size_t)N_ROWS * DIM);
    }
}

// Round 5
// 427.497 us; speedup vs baseline: 3.3904x; 1.1256x over previous
//
#include <hip/hip_runtime.h>

// Vector Quantizer, MFMA split-bf16 path + exact fp32 refine (row-major Et).
// inputs  d_in[0]: float32 X [32768, 256]
// emb     d_in[1]: float32 E [256, 4096]
// d_out: [8388608 floats e_k] + [1 float loss]
//
// dot(x,e) ~ 3 bf16 MFMAs: xh*eh + xh*el + xl*eh (fp32 accum).
// dist_mfma v2: A (X hi/lo) lives in registers for the whole block (loaded
// once); only B (E^T hi/lo) is staged to LDS, double-buffered, stage issued
// BEFORE compute each kt so the pre-barrier drain overlaps MFMA work.
// XCD-aware swizzle: each XCD owns 32 contiguous rowblocks x all 8 strips.
// Top-2 per (row, strip) -> fused refine(exact fp32)+gather+loss.

typedef unsigned short ushort_t;
typedef unsigned int uint_t;
typedef __attribute__((ext_vector_type(8))) short bf16x8;
typedef __attribute__((ext_vector_type(4))) float f32x4;

#define N_ROWS 32768
#define DIM 256
#define K_CODES 4096
#define NKS 8            // col strips (512 cols each)
#define GATHER_BLOCKS 512
#define RG_BLOCKS (N_ROWS / 32)   // fused refine+gather: 32 rows/block

// ---- ws layout (mfma path), bytes ----
// Ehi      [0,       2097152)   bf16 [4096][256]   (dead after dist_mfma)
// Elo      [2097152, 4194304)                      (dead after dist_mfma)
// Et       [0,       4194304)   fp32 [4096][256]   (built after dist_mfma)
// candi2   [4194304, 6291456)   int [32768][8 strips][2]
// esq      [6291456, 6307840)   float[4096]
// partials [6438912, 6443008)   float[1024]
#define WS_NEEDED (8u * 1024u * 1024u)

__device__ __forceinline__ unsigned short bf16_rne(float x) {
    unsigned u = __builtin_bit_cast(unsigned, x);
    unsigned r = u + 0x7fffu + ((u >> 16) & 1u);
    return (unsigned short)(r >> 16);
}
__device__ __forceinline__ float bf16_f(unsigned short h) {
    unsigned u = ((unsigned)h) << 16;
    return __builtin_bit_cast(float, u);
}
// total-order "better": smaller dist, tie -> smaller index
__device__ __forceinline__ bool better(float d, int c, float v, int i) {
    return (d < v) || (d == v && c < i);
}

// ---------------- prep: X -> Xh/Xl (bf16 split), into d_out ----------------
__global__ void prep_x(const float* __restrict__ X, ushort_t* __restrict__ Xh,
                       ushort_t* __restrict__ Xl) {
    int i = blockIdx.x * 256 + threadIdx.x;   // float4 index
    float4 v = ((const float4*)X)[i];
    ushort4 h, l;
    h.x = bf16_rne(v.x); l.x = bf16_rne(v.x - bf16_f(h.x));
    h.y = bf16_rne(v.y); l.y = bf16_rne(v.y - bf16_f(h.y));
    h.z = bf16_rne(v.z); l.z = bf16_rne(v.z - bf16_f(h.z));
    h.w = bf16_rne(v.w); l.w = bf16_rne(v.w - bf16_f(h.w));
    ((ushort4*)Xh)[i] = h;
    ((ushort4*)Xl)[i] = l;
}

// ------------- prep: E [256][4096] -> E^T hi/lo [4096][256] bf16 -----------
__global__ void prep_e(const float* __restrict__ E, ushort_t* __restrict__ Ehi,
                       ushort_t* __restrict__ Elo) {
    __shared__ ushort_t sh[64][66];
    __shared__ ushort_t sl[64][66];
    const int t = threadIdx.x;
    const int kbase = blockIdx.x * 64;
    const int dbase = blockIdx.y * 64;
#pragma unroll
    for (int i = 0; i < 16; ++i) {
        int lin = i * 256 + t;
        int dl = lin >> 6, kl = lin & 63;
        float v = E[(size_t)(dbase + dl) * K_CODES + kbase + kl];
        unsigned short h = bf16_rne(v);
        unsigned short l = bf16_rne(v - bf16_f(h));
        sh[kl][dl] = h;
        sl[kl][dl] = l;
    }
    __syncthreads();
#pragma unroll
    for (int i = 0; i < 8; ++i) {
        int lin = i * 256 + t;
        int kl = lin >> 5, d2 = (lin & 31) * 2;
        uint_t vh = (uint_t)sh[kl][d2] | ((uint_t)sh[kl][d2 + 1] << 16);
        uint_t vl = (uint_t)sl[kl][d2] | ((uint_t)sl[kl][d2 + 1] << 16);
        *(uint_t*)&Ehi[(size_t)(kbase + kl) * DIM + dbase + d2] = vh;
        *(uint_t*)&Elo[(size_t)(kbase + kl) * DIM + dbase + d2] = vl;
    }
}

// ------------- prep: E [256][4096] -> Et fp32 [4096][256] (exact) ----------
__global__ void prep_et(const float* __restrict__ E, float* __restrict__ Et) {
    __shared__ float s[64][65];
    const int t = threadIdx.x;
    const int kbase = blockIdx.x * 64;
    const int dbase = blockIdx.y * 64;
#pragma unroll
    for (int i = 0; i < 16; ++i) {
        int lin = i * 256 + t;
        int dl = lin >> 6, kl = lin & 63;
        s[kl][dl] = E[(size_t)(dbase + dl) * K_CODES + kbase + kl];
    }
    __syncthreads();
#pragma unroll
    for (int i = 0; i < 16; ++i) {
        int lin = i * 256 + t;
        int kl = lin >> 6, dl = lin & 63;
        Et[(size_t)(kbase + kl) * DIM + dbase + dl] = s[kl][dl];
    }
}

// ---------------- esq[k] = sum_d E[d][k]^2 (fp32, from original E) ---------
__global__ void esq_kernel(const float* __restrict__ E, float* __restrict__ esq) {
    __shared__ float red[16][17];
    int t = threadIdx.x;
    int kk = t & 15, dg = t >> 4;
    int k = blockIdx.x * 16 + kk;
    float a = 0.f;
#pragma unroll
    for (int it = 0; it < 16; ++it) {
        float e = E[(dg + it * 16) * K_CODES + k];
        a = fmaf(e, e, a);
    }
    red[dg][kk] = a;
    __syncthreads();
    if (t < 16) {
        float s = 0.f;
#pragma unroll
        for (int g = 0; g < 16; ++g) s += red[g][t];
        esq[blockIdx.x * 16 + t] = s;
    }
}

// ---------------- main: MFMA distance + per-strip top-2 (v2) ---------------
// grid (NKS, 256) flattened+swizzled: xcd = wgid%8 owns rowblocks
// [xcd*32, xcd*32+32) x all strips; within XCD, strip varies fastest.
// 256 threads = 4 waves; wave w owns rows [w*32, w*32+32) (2 m-blocks).
// A (X hi/lo) fragments in registers (loaded once); B (E^T hi/lo) staged to
// LDS double-buffered, 16 KB per kt step, stage issued before compute.
__global__ __launch_bounds__(256, 2) void dist_mfma(
    const ushort_t* __restrict__ Xh, const ushort_t* __restrict__ Xl,
    const ushort_t* __restrict__ Ehi, const ushort_t* __restrict__ Elo,
    const float* __restrict__ esq, int* __restrict__ candi2) {
    __shared__ short lds[16384];   // 32 KB: buf p at p*8192 shorts,
                                   // within buf: Bh [0,4096) Bl [4096,8192)
    const int t = threadIdx.x;
    const int l = t & 63, w = t >> 6;
    const int l15 = l & 15, lg = l >> 4;

    // bijective XCD swizzle (2048 blocks = 8 XCD x 256)
    const int wgid = blockIdx.x + blockIdx.y * NKS;
    const int xcd = wgid & 7, pos = wgid >> 3;
    const int ks = pos & 7;
    const int rowbase = (xcd * 32 + (pos >> 3)) * 128;

    // ---- A prologue: 2 m-blocks x 8 kt, hi+lo fragments -> 128 VGPRs
    bf16x8 ah[2][8], al[2][8];
#pragma unroll
    for (int m = 0; m < 2; ++m) {
        const size_t base = (size_t)(rowbase + w * 32 + m * 16 + l15) * DIM + lg * 8;
#pragma unroll
        for (int kt = 0; kt < 8; ++kt) {
            ah[m][kt] = *(const bf16x8*)(Xh + base + kt * 32);
            al[m][kt] = *(const bf16x8*)(Xl + base + kt * 32);
        }
    }

    const int n0 = 2 * w, n1 = 2 * w + 1;   // B n-blocks staged by this wave

#define GLDS(srcp, dstoff)                                                      \
    __builtin_amdgcn_global_load_lds(                                           \
        (const __attribute__((address_space(1))) void*)(srcp),                  \
        (__attribute__((address_space(3))) void*)&lds[dstoff], 16, 0, 0)
#define STAGE(pbuf, cbase, ktv) do {                                            \
    const size_t o0 = (size_t)((cbase) + n0 * 16 + l15) * DIM + (ktv) * 32 + lg * 8; \
    const size_t o1 = (size_t)((cbase) + n1 * 16 + l15) * DIM + (ktv) * 32 + lg * 8; \
    GLDS(Ehi + o0, (pbuf) * 8192 + n0 * 512);                                   \
    GLDS(Ehi + o1, (pbuf) * 8192 + n1 * 512);                                   \
    GLDS(Elo + o0, (pbuf) * 8192 + 4096 + n0 * 512);                            \
    GLDS(Elo + o1, (pbuf) * 8192 + 4096 + n1 * 512);                            \
} while (0)

    float v1[2][4], v2[2][4];
    int   i1[2][4], i2[2][4];
#pragma unroll
    for (int m = 0; m < 2; ++m)
#pragma unroll
        for (int q = 0; q < 4; ++q) {
            v1[m][q] = 3.4e38f; v2[m][q] = 3.4e38f;
            i1[m][q] = 0x7fffffff; i2[m][q] = 0x7fffffff;
        }

    STAGE(0, ks * 512, 0);
    __syncthreads();

#pragma unroll 1
    for (int ct = 0; ct < 4; ++ct) {
        const int cb = ks * 512 + ct * 128;

        f32x4 acc[2][8];
#pragma unroll
        for (int m = 0; m < 2; ++m)
#pragma unroll
            for (int n = 0; n < 8; ++n) acc[m][n] = (f32x4){0.f, 0.f, 0.f, 0.f};

#pragma unroll
        for (int kt = 0; kt < 8; ++kt) {
            const int cur = kt & 1;
            // stage next (ct,kt) into the other buffer BEFORE compute
            if (kt < 7) {
                STAGE(cur ^ 1, cb, kt + 1);
            } else if (ct < 3) {
                STAGE(cur ^ 1, cb + 128, 0);
            }
            // compute current kt from buf[cur] (A from registers)
#pragma unroll
            for (int n = 0; n < 8; ++n) {
                const bf16x8 bh = *(const bf16x8*)&lds[cur * 8192 + n * 512 + l * 8];
                const bf16x8 bl = *(const bf16x8*)&lds[cur * 8192 + 4096 + n * 512 + l * 8];
#pragma unroll
                for (int m = 0; m < 2; ++m) {
                    acc[m][n] = __builtin_amdgcn_mfma_f32_16x16x32_bf16(
                        ah[m][kt], bh, acc[m][n], 0, 0, 0);
                    acc[m][n] = __builtin_amdgcn_mfma_f32_16x16x32_bf16(
                        ah[m][kt], bl, acc[m][n], 0, 0, 0);
                    acc[m][n] = __builtin_amdgcn_mfma_f32_16x16x32_bf16(
                        al[m][kt], bh, acc[m][n], 0, 0, 0);
                }
            }
            // barrier: compiler drains vmcnt (next stage) + lgkm; all waves
            // finished reading buf[cur] -> safe to overwrite next iteration
            __syncthreads();
        }

        // epilogue: dist = esq - 2*dot, top-2 update per (m,q)
#pragma unroll
        for (int n = 0; n < 8; ++n) {
            const int col = cb + n * 16 + l15;
            const float eq = esq[col];
#pragma unroll
            for (int m = 0; m < 2; ++m)
#pragma unroll
                for (int q = 0; q < 4; ++q) {
                    const float d = fmaf(-2.f, acc[m][n][q], eq);
                    if (better(d, col, v1[m][q], i1[m][q])) {
                        v2[m][q] = v1[m][q]; i2[m][q] = i1[m][q];
                        v1[m][q] = d;        i1[m][q] = col;
                    } else if (better(d, col, v2[m][q], i2[m][q])) {
                        v2[m][q] = d; i2[m][q] = col;
                    }
                }
        }
    }
#undef STAGE
#undef GLDS

    // cross-lane top-2 merge over the 16 col-lanes (indices all distinct)
#pragma unroll
    for (int m = 0; m < 2; ++m)
#pragma unroll
        for (int q = 0; q < 4; ++q) {
            float a1 = v1[m][q], a2 = v2[m][q];
            int   b1 = i1[m][q], b2 = i2[m][q];
#pragma unroll
            for (int msk = 8; msk >= 1; msk >>= 1) {
                const float c1 = __shfl_xor(a1, msk, 64);
                const int   d1 = __shfl_xor(b1, msk, 64);
                const float c2 = __shfl_xor(a2, msk, 64);
                const int   d2 = __shfl_xor(b2, msk, 64);
                if (better(c1, d1, a1, b1)) {
                    if (better(a1, b1, c2, d2)) { a2 = a1; b2 = b1; }
                    else                        { a2 = c2; b2 = d2; }
                    a1 = c1; b1 = d1;
                } else {
                    if (better(c1, d1, a2, b2)) { a2 = c1; b2 = d1; }
                }
            }
            if (l15 == 0) {
                const int row = rowbase + w * 32 + m * 16 + lg * 4 + q;
                candi2[(row * NKS + ks) * 2 + 0] = b1;
                candi2[(row * NKS + ks) * 2 + 1] = b2;
            }
        }
}

// ------- fused refine (exact fp32 over 16 cands) + gather + loss -----------
// 4 waves/block, each wave handles 8 rows sequentially. Refine: lane =
// (cand 0..15) x (dim-group 0..3); after xor-16/32 sum + xor-8..1 argmin,
// ALL lanes hold the winning index. Gather: 64 lanes x float4.
__global__ void refine_gather(const float* __restrict__ X, const float* __restrict__ Et,
                              const int* __restrict__ cand,
                              float* __restrict__ out, float* __restrict__ partials) {
    const int w = threadIdx.x >> 6, l = threadIdx.x & 63;
    const int cs = l & 15, dg = l >> 4;
    const int row0 = blockIdx.x * 32 + w * 8;
    float lsum = 0.f;

#pragma unroll 1
    for (int rr = 0; rr < 8; ++rr) {
        const int row = row0 + rr;
        const int c = cand[row * 16 + cs];
        const float4* ep = (const float4*)(Et + (size_t)c * DIM + dg * 64);
        const float4* xp = (const float4*)(X + (size_t)row * DIM + dg * 64);
        float p = 0.f;
#pragma unroll
        for (int j = 0; j < 16; ++j) {
            const float4 e = ep[j];
            const float4 x = xp[j];
            p = fmaf(e.x, fmaf(-2.f, x.x, e.x), p);
            p = fmaf(e.y, fmaf(-2.f, x.y, e.y), p);
            p = fmaf(e.z, fmaf(-2.f, x.z, e.z), p);
            p = fmaf(e.w, fmaf(-2.f, x.w, e.w), p);
        }
        p += __shfl_xor(p, 16, 64);
        p += __shfl_xor(p, 32, 64);
        float v = p; int id = c;
#pragma unroll
        for (int m = 8; m >= 1; m >>= 1) {
            const float v2 = __shfl_xor(v, m, 64);
            const int  id2 = __shfl_xor(id, m, 64);
            if (v2 < v || (v2 == v && id2 < id)) { v = v2; id = id2; }
        }
        // gather + loss (all lanes agree on id)
        const float4 x = *(const float4*)(X + (size_t)row * DIM + l * 4);
        const float4 q = *(const float4*)(Et + (size_t)id * DIM + l * 4);
        *(float4*)(out + (size_t)row * DIM + l * 4) = q;
        const float d0 = x.x - q.x, d1 = x.y - q.y, d2 = x.z - q.z, d3 = x.w - q.w;
        lsum += d0 * d0 + d1 * d1 + d2 * d2 + d3 * d3;
    }
#pragma unroll
    for (int m = 32; m >= 1; m >>= 1) lsum += __shfl_xor(lsum, m, 64);
    __shared__ float ws4[4];
    if (l == 0) ws4[w] = lsum;
    __syncthreads();
    if (threadIdx.x == 0) partials[blockIdx.x] = (ws4[0] + ws4[1]) + (ws4[2] + ws4[3]);
}

// -------- fallback fp32 dist (round-1 proven path, used if ws too small) ---
__global__ void dist_fp32(const float* __restrict__ X, const float* __restrict__ E,
                          const float* __restrict__ esq,
                          float* __restrict__ candv, int* __restrict__ candi) {
    __shared__ float Xs[8][128];
    __shared__ float Es[8][128];
    const int t = threadIdx.x;
    const int tx = t & 15;
    const int ty = t >> 4;
    const int rowbase = blockIdx.x * 128;
    const int ks = blockIdx.y;

    float minv[8];
    int   mini[8];
#pragma unroll
    for (int i = 0; i < 8; ++i) { minv[i] = 3.4e38f; mini[i] = 0; }

    for (int kt = 0; kt < 8; ++kt) {
        const int kbase = ks * 1024 + kt * 128;
        float acc[8][8];
#pragma unroll
        for (int i = 0; i < 8; ++i)
#pragma unroll
            for (int j = 0; j < 8; ++j) acc[i][j] = 0.f;

        for (int dc = 0; dc < DIM / 8; ++dc) {
            const int d0 = dc * 8;
            {
                const int row = t >> 1;
                const int dsl = (t & 1) * 4;
                const float4 xv = *(const float4*)(X + (size_t)(rowbase + row) * DIM + d0 + dsl);
                Xs[dsl + 0][row] = xv.x; Xs[dsl + 1][row] = xv.y;
                Xs[dsl + 2][row] = xv.z; Xs[dsl + 3][row] = xv.w;
            }
            {
                const int dr = t >> 5;
                const int c4 = (t & 31) * 4;
                const float4 ev = *(const float4*)(E + (size_t)(d0 + dr) * K_CODES + kbase + c4);
                *(float4*)&Es[dr][c4] = ev;
            }
            __syncthreads();
#pragma unroll
            for (int d = 0; d < 8; ++d) {
                float xr[8], er[8];
                *(float4*)&xr[0] = *(const float4*)&Xs[d][ty * 8];
                *(float4*)&xr[4] = *(const float4*)&Xs[d][ty * 8 + 4];
                *(float4*)&er[0] = *(const float4*)&Es[d][tx * 8];
                *(float4*)&er[4] = *(const float4*)&Es[d][tx * 8 + 4];
#pragma unroll
                for (int i = 0; i < 8; ++i)
#pragma unroll
                    for (int j = 0; j < 8; ++j)
                        acc[i][j] = fmaf(xr[i], er[j], acc[i][j]);
            }
            __syncthreads();
        }
        float eq[8];
        *(float4*)&eq[0] = *(const float4*)(esq + kbase + tx * 8);
        *(float4*)&eq[4] = *(const float4*)(esq + kbase + tx * 8 + 4);
#pragma unroll
        for (int i = 0; i < 8; ++i)
#pragma unroll
            for (int j = 0; j < 8; ++j) {
                const float dist = fmaf(-2.f, acc[i][j], eq[j]);
                if (dist < minv[i]) { minv[i] = dist; mini[i] = kbase + tx * 8 + j; }
            }
    }
#pragma unroll
    for (int i = 0; i < 8; ++i) {
        float v = minv[i];
        int   id = mini[i];
#pragma unroll
        for (int m = 8; m >= 1; m >>= 1) {
            const float v2 = __shfl_xor(v, m, 64);
            const int   i2 = __shfl_xor(id, m, 64);
            if (v2 < v || (v2 == v && i2 < id)) { v = v2; id = i2; }
        }
        if (tx == 0) {
            const int row = rowbase + ty * 8 + i;
            candv[row * 4 + ks] = v;
            candi[row * 4 + ks] = id;
        }
    }
}

__global__ void gather_loss(const float* __restrict__ X, const float* __restrict__ E,
                            const float* __restrict__ candv, const int* __restrict__ candi,
                            float* __restrict__ out, float* __restrict__ partials,
                            int nks) {
    const int w = threadIdx.x >> 6;
    const int l = threadIdx.x & 63;
    const int rowbase = blockIdx.x * (N_ROWS / GATHER_BLOCKS);
    float lsum = 0.f;

    for (int rr = w; rr < N_ROWS / GATHER_BLOCKS; rr += 4) {
        const int row = rowbase + rr;
        float bv = candv[row * nks];
        int   bi = candi[row * nks];
        for (int s = 1; s < nks; ++s) {
            const float v = candv[row * nks + s];
            const int  id = candi[row * nks + s];
            if (v < bv || (v == bv && id < bi)) { bv = v; bi = id; }
        }
        const float4 x = *(const float4*)(X + (size_t)row * DIM + l * 4);
        const float q0 = E[(size_t)(l * 4 + 0) * K_CODES + bi];
        const float q1 = E[(size_t)(l * 4 + 1) * K_CODES + bi];
        const float q2 = E[(size_t)(l * 4 + 2) * K_CODES + bi];
        const float q3 = E[(size_t)(l * 4 + 3) * K_CODES + bi];
        float4 q; q.x = q0; q.y = q1; q.z = q2; q.w = q3;
        *(float4*)(out + (size_t)row * DIM + l * 4) = q;
        const float d0 = x.x - q0, d1 = x.y - q1, d2 = x.z - q2, d3 = x.w - q3;
        lsum += d0 * d0 + d1 * d1 + d2 * d2 + d3 * d3;
    }
#pragma unroll
    for (int m = 32; m >= 1; m >>= 1) lsum += __shfl_xor(lsum, m, 64);
    __shared__ float ws4[4];
    if (l == 0) ws4[w] = lsum;
    __syncthreads();
    if (threadIdx.x == 0) partials[blockIdx.x] = (ws4[0] + ws4[1]) + (ws4[2] + ws4[3]);
}

__global__ void finalize(const float* __restrict__ partials, float* __restrict__ out_loss,
                         int npart) {
    __shared__ double s[256];
    double a = 0.0;
    for (int i = threadIdx.x; i < npart; i += 256) a += (double)partials[i];
    s[threadIdx.x] = a;
    __syncthreads();
    for (int st = 128; st > 0; st >>= 1) {
        if (threadIdx.x < st) s[threadIdx.x] += s[threadIdx.x + st];
        __syncthreads();
    }
    if (threadIdx.x == 0)
        out_loss[0] = (float)(1.25 * s[0] / (double)(N_ROWS * DIM));
}

extern "C" void kernel_launch(void* const* d_in, const int* in_sizes, int n_in,
                              void* d_out, int out_size, void* d_ws, size_t ws_size,
                              hipStream_t stream) {
    const float* X = (const float*)d_in[0];
    const float* E = (const float*)d_in[1];
    float* out = (float*)d_out;

    if (ws_size >= (size_t)WS_NEEDED) {
        // ---------------- MFMA path ----------------
        ushort_t* Ehi      = (ushort_t*)((char*)d_ws + 0);
        ushort_t* Elo      = (ushort_t*)((char*)d_ws + 2097152);
        float*    Et       = (float*)   ((char*)d_ws + 0);        // after dist_mfma
        int*      candi2   = (int*)     ((char*)d_ws + 4194304);
        float*    esq      = (float*)   ((char*)d_ws + 6291456);
        float*    partials = (float*)   ((char*)d_ws + 6438912);
        ushort_t* Xh       = (ushort_t*)d_out;                    // 16.78 MB
        ushort_t* Xl       = Xh + (size_t)N_ROWS * DIM;           // 16.78 MB

        prep_x<<<(N_ROWS * DIM / 4) / 256, 256, 0, stream>>>(X, Xh, Xl);
        prep_e<<<dim3(K_CODES / 64, DIM / 64), 256, 0, stream>>>(E, Ehi, Elo);
        esq_kernel<<<K_CODES / 16, 256, 0, stream>>>(E, esq);
        dist_mfma<<<dim3(NKS, N_ROWS / 128), 256, 0, stream>>>(
            Xh, Xl, Ehi, Elo, esq, candi2);
        prep_et<<<dim3(K_CODES / 64, DIM / 64), 256, 0, stream>>>(E, Et);
        refine_gather<<<RG_BLOCKS, 256, 0, stream>>>(X, Et, candi2, out, partials);
        finalize<<<1, 256, 0, stream>>>(partials, out + (size_t)N_ROWS * DIM, RG_BLOCKS);
    } else {
        // ---------------- fallback: round-1 fp32 path (needs ~1.07 MB) -----
        float* esq      = (float*)((char*)d_ws + 0);
        float* candv    = (float*)((char*)d_ws + 16384);
        int*   candi    = (int*)  ((char*)d_ws + 540672);
        float* partials = (float*)((char*)d_ws + 1064960);

        esq_kernel<<<K_CODES / 16, 256, 0, stream>>>(E, esq);
        dist_fp32<<<dim3(N_ROWS / 128, 4), 256, 0, stream>>>(X, E, esq, candv, candi);
        gather_loss<<<GATHER_BLOCKS, 256, 0, stream>>>(X, E, candv, candi, out,
                                                       partials, 4);
        finalize<<<1, 256, 0, stream>>>(partials, out + (size_t)N_ROWS * DIM,
                                        GATHER_BLOCKS);
    }
}

// Round 6
// 426.660 us; speedup vs baseline: 3.3971x; 1.0020x over previous
//
#include <hip/hip_runtime.h>

// Vector Quantizer, MFMA split-bf16 path + exact fp32 refine (row-major Et).
// inputs  d_in[0]: float32 X [32768, 256]
// emb     d_in[1]: float32 E [256, 4096]
// d_out: [8388608 floats e_k] + [1 float loss]
//
// dot(x,e) ~ 3 bf16 MFMAs: xh*eh + xh*el + xl*eh (fp32 accum).
// dist_mfma v3 = v2 + forced 2-waves/EU (256-VGPR budget) so the A hi/lo
// fragment file (128 VGPRs) + acc (64, AGPR-eligible) + top-2 state stays
// register-resident (v2 spilled ~200 MB to scratch at the 128-reg cap).
// XCD-aware swizzle: each XCD owns 32 contiguous rowblocks x all 8 strips.
// Top-2 per (row, strip) -> fused refine(exact fp32)+gather+loss.

typedef unsigned short ushort_t;
typedef unsigned int uint_t;
typedef __attribute__((ext_vector_type(8))) short bf16x8;
typedef __attribute__((ext_vector_type(4))) float f32x4;

#define N_ROWS 32768
#define DIM 256
#define K_CODES 4096
#define NKS 8            // col strips (512 cols each)
#define GATHER_BLOCKS 512
#define RG_BLOCKS (N_ROWS / 32)   // fused refine+gather: 32 rows/block

// ---- ws layout (mfma path), bytes ----
// Ehi      [0,       2097152)   bf16 [4096][256]   (dead after dist_mfma)
// Elo      [2097152, 4194304)                      (dead after dist_mfma)
// Et       [0,       4194304)   fp32 [4096][256]   (built after dist_mfma)
// candi2   [4194304, 6291456)   int [32768][8 strips][2]
// esq      [6291456, 6307840)   float[4096]
// partials [6438912, 6443008)   float[1024]
#define WS_NEEDED (8u * 1024u * 1024u)

__device__ __forceinline__ unsigned short bf16_rne(float x) {
    unsigned u = __builtin_bit_cast(unsigned, x);
    unsigned r = u + 0x7fffu + ((u >> 16) & 1u);
    return (unsigned short)(r >> 16);
}
__device__ __forceinline__ float bf16_f(unsigned short h) {
    unsigned u = ((unsigned)h) << 16;
    return __builtin_bit_cast(float, u);
}
// total-order "better": smaller dist, tie -> smaller index
__device__ __forceinline__ bool better(float d, int c, float v, int i) {
    return (d < v) || (d == v && c < i);
}

// ---------------- prep: X -> Xh/Xl (bf16 split), into d_out ----------------
__global__ void prep_x(const float* __restrict__ X, ushort_t* __restrict__ Xh,
                       ushort_t* __restrict__ Xl) {
    int i = blockIdx.x * 256 + threadIdx.x;   // float4 index
    float4 v = ((const float4*)X)[i];
    ushort4 h, l;
    h.x = bf16_rne(v.x); l.x = bf16_rne(v.x - bf16_f(h.x));
    h.y = bf16_rne(v.y); l.y = bf16_rne(v.y - bf16_f(h.y));
    h.z = bf16_rne(v.z); l.z = bf16_rne(v.z - bf16_f(h.z));
    h.w = bf16_rne(v.w); l.w = bf16_rne(v.w - bf16_f(h.w));
    ((ushort4*)Xh)[i] = h;
    ((ushort4*)Xl)[i] = l;
}

// ------------- prep: E [256][4096] -> E^T hi/lo [4096][256] bf16 -----------
__global__ void prep_e(const float* __restrict__ E, ushort_t* __restrict__ Ehi,
                       ushort_t* __restrict__ Elo) {
    __shared__ ushort_t sh[64][66];
    __shared__ ushort_t sl[64][66];
    const int t = threadIdx.x;
    const int kbase = blockIdx.x * 64;
    const int dbase = blockIdx.y * 64;
#pragma unroll
    for (int i = 0; i < 16; ++i) {
        int lin = i * 256 + t;
        int dl = lin >> 6, kl = lin & 63;
        float v = E[(size_t)(dbase + dl) * K_CODES + kbase + kl];
        unsigned short h = bf16_rne(v);
        unsigned short l = bf16_rne(v - bf16_f(h));
        sh[kl][dl] = h;
        sl[kl][dl] = l;
    }
    __syncthreads();
#pragma unroll
    for (int i = 0; i < 8; ++i) {
        int lin = i * 256 + t;
        int kl = lin >> 5, d2 = (lin & 31) * 2;
        uint_t vh = (uint_t)sh[kl][d2] | ((uint_t)sh[kl][d2 + 1] << 16);
        uint_t vl = (uint_t)sl[kl][d2] | ((uint_t)sl[kl][d2 + 1] << 16);
        *(uint_t*)&Ehi[(size_t)(kbase + kl) * DIM + dbase + d2] = vh;
        *(uint_t*)&Elo[(size_t)(kbase + kl) * DIM + dbase + d2] = vl;
    }
}

// ------------- prep: E [256][4096] -> Et fp32 [4096][256] (exact) ----------
__global__ void prep_et(const float* __restrict__ E, float* __restrict__ Et) {
    __shared__ float s[64][65];
    const int t = threadIdx.x;
    const int kbase = blockIdx.x * 64;
    const int dbase = blockIdx.y * 64;
#pragma unroll
    for (int i = 0; i < 16; ++i) {
        int lin = i * 256 + t;
        int dl = lin >> 6, kl = lin & 63;
        s[kl][dl] = E[(size_t)(dbase + dl) * K_CODES + kbase + kl];
    }
    __syncthreads();
#pragma unroll
    for (int i = 0; i < 16; ++i) {
        int lin = i * 256 + t;
        int kl = lin >> 6, dl = lin & 63;
        Et[(size_t)(kbase + kl) * DIM + dbase + dl] = s[kl][dl];
    }
}

// ---------------- esq[k] = sum_d E[d][k]^2 (fp32, from original E) ---------
__global__ void esq_kernel(const float* __restrict__ E, float* __restrict__ esq) {
    __shared__ float red[16][17];
    int t = threadIdx.x;
    int kk = t & 15, dg = t >> 4;
    int k = blockIdx.x * 16 + kk;
    float a = 0.f;
#pragma unroll
    for (int it = 0; it < 16; ++it) {
        float e = E[(dg + it * 16) * K_CODES + k];
        a = fmaf(e, e, a);
    }
    red[dg][kk] = a;
    __syncthreads();
    if (t < 16) {
        float s = 0.f;
#pragma unroll
        for (int g = 0; g < 16; ++g) s += red[g][t];
        esq[blockIdx.x * 16 + t] = s;
    }
}

// ---------------- main: MFMA distance + per-strip top-2 (v3) ---------------
// grid (NKS, 256) flattened+swizzled: xcd = wgid%8 owns rowblocks
// [xcd*32, xcd*32+32) x all strips; within XCD, strip varies fastest.
// 256 threads = 4 waves; wave w owns rows [w*32, w*32+32) (2 m-blocks).
// A (X hi/lo) fragments in registers (loaded once, 128 VGPRs); B (E^T hi/lo)
// staged to LDS double-buffered, 16 KB per kt step, stage issued before
// compute. waves_per_eu(2,2): 256-VGPR budget -> no scratch spill.
__global__ __launch_bounds__(256)
__attribute__((amdgpu_waves_per_eu(2, 2)))
void dist_mfma(
    const ushort_t* __restrict__ Xh, const ushort_t* __restrict__ Xl,
    const ushort_t* __restrict__ Ehi, const ushort_t* __restrict__ Elo,
    const float* __restrict__ esq, int* __restrict__ candi2) {
    __shared__ short lds[16384];   // 32 KB: buf p at p*8192 shorts,
                                   // within buf: Bh [0,4096) Bl [4096,8192)
    const int t = threadIdx.x;
    const int l = t & 63, w = t >> 6;
    const int l15 = l & 15, lg = l >> 4;

    // bijective XCD swizzle (2048 blocks = 8 XCD x 256)
    const int wgid = blockIdx.x + blockIdx.y * NKS;
    const int xcd = wgid & 7, pos = wgid >> 3;
    const int ks = pos & 7;
    const int rowbase = (xcd * 32 + (pos >> 3)) * 128;

    const int n0 = 2 * w, n1 = 2 * w + 1;   // B n-blocks staged by this wave

#define GLDS(srcp, dstoff)                                                      \
    __builtin_amdgcn_global_load_lds(                                           \
        (const __attribute__((address_space(1))) void*)(srcp),                  \
        (__attribute__((address_space(3))) void*)&lds[dstoff], 16, 0, 0)
#define STAGE(pbuf, cbase, ktv) do {                                            \
    const size_t o0 = (size_t)((cbase) + n0 * 16 + l15) * DIM + (ktv) * 32 + lg * 8; \
    const size_t o1 = (size_t)((cbase) + n1 * 16 + l15) * DIM + (ktv) * 32 + lg * 8; \
    GLDS(Ehi + o0, (pbuf) * 8192 + n0 * 512);                                   \
    GLDS(Ehi + o1, (pbuf) * 8192 + n1 * 512);                                   \
    GLDS(Elo + o0, (pbuf) * 8192 + 4096 + n0 * 512);                            \
    GLDS(Elo + o1, (pbuf) * 8192 + 4096 + n1 * 512);                            \
} while (0)

    // issue first B-stage before the A prologue so DMA overlaps A latency
    STAGE(0, ks * 512, 0);

    // ---- A prologue: 2 m-blocks x 8 kt, hi+lo fragments -> 128 VGPRs
    bf16x8 ah[2][8], al[2][8];
#pragma unroll
    for (int m = 0; m < 2; ++m) {
        const size_t base = (size_t)(rowbase + w * 32 + m * 16 + l15) * DIM + lg * 8;
#pragma unroll
        for (int kt = 0; kt < 8; ++kt) {
            ah[m][kt] = *(const bf16x8*)(Xh + base + kt * 32);
            al[m][kt] = *(const bf16x8*)(Xl + base + kt * 32);
        }
    }

    float v1[2][4], v2[2][4];
    int   i1[2][4], i2[2][4];
#pragma unroll
    for (int m = 0; m < 2; ++m)
#pragma unroll
        for (int q = 0; q < 4; ++q) {
            v1[m][q] = 3.4e38f; v2[m][q] = 3.4e38f;
            i1[m][q] = 0x7fffffff; i2[m][q] = 0x7fffffff;
        }

    __syncthreads();

#pragma unroll 1
    for (int ct = 0; ct < 4; ++ct) {
        const int cb = ks * 512 + ct * 128;

        f32x4 acc[2][8];
#pragma unroll
        for (int m = 0; m < 2; ++m)
#pragma unroll
            for (int n = 0; n < 8; ++n) acc[m][n] = (f32x4){0.f, 0.f, 0.f, 0.f};

#pragma unroll
        for (int kt = 0; kt < 8; ++kt) {
            const int cur = kt & 1;
            // stage next (ct,kt) into the other buffer BEFORE compute
            if (kt < 7) {
                STAGE(cur ^ 1, cb, kt + 1);
            } else if (ct < 3) {
                STAGE(cur ^ 1, cb + 128, 0);
            }
            // compute current kt from buf[cur] (A from registers)
#pragma unroll
            for (int n = 0; n < 8; ++n) {
                const bf16x8 bh = *(const bf16x8*)&lds[cur * 8192 + n * 512 + l * 8];
                const bf16x8 bl = *(const bf16x8*)&lds[cur * 8192 + 4096 + n * 512 + l * 8];
#pragma unroll
                for (int m = 0; m < 2; ++m) {
                    acc[m][n] = __builtin_amdgcn_mfma_f32_16x16x32_bf16(
                        ah[m][kt], bh, acc[m][n], 0, 0, 0);
                    acc[m][n] = __builtin_amdgcn_mfma_f32_16x16x32_bf16(
                        ah[m][kt], bl, acc[m][n], 0, 0, 0);
                    acc[m][n] = __builtin_amdgcn_mfma_f32_16x16x32_bf16(
                        al[m][kt], bh, acc[m][n], 0, 0, 0);
                }
            }
            // barrier: drains vmcnt (next stage) + lgkm; all waves finished
            // reading buf[cur] -> safe to overwrite next iteration
            __syncthreads();
        }

        // epilogue: dist = esq - 2*dot, top-2 update per (m,q)
#pragma unroll
        for (int n = 0; n < 8; ++n) {
            const int col = cb + n * 16 + l15;
            const float eq = esq[col];
#pragma unroll
            for (int m = 0; m < 2; ++m)
#pragma unroll
                for (int q = 0; q < 4; ++q) {
                    const float d = fmaf(-2.f, acc[m][n][q], eq);
                    if (better(d, col, v1[m][q], i1[m][q])) {
                        v2[m][q] = v1[m][q]; i2[m][q] = i1[m][q];
                        v1[m][q] = d;        i1[m][q] = col;
                    } else if (better(d, col, v2[m][q], i2[m][q])) {
                        v2[m][q] = d; i2[m][q] = col;
                    }
                }
        }
    }
#undef STAGE
#undef GLDS

    // cross-lane top-2 merge over the 16 col-lanes (indices all distinct)
#pragma unroll
    for (int m = 0; m < 2; ++m)
#pragma unroll
        for (int q = 0; q < 4; ++q) {
            float a1 = v1[m][q], a2 = v2[m][q];
            int   b1 = i1[m][q], b2 = i2[m][q];
#pragma unroll
            for (int msk = 8; msk >= 1; msk >>= 1) {
                const float c1 = __shfl_xor(a1, msk, 64);
                const int   d1 = __shfl_xor(b1, msk, 64);
                const float c2 = __shfl_xor(a2, msk, 64);
                const int   d2 = __shfl_xor(b2, msk, 64);
                if (better(c1, d1, a1, b1)) {
                    if (better(a1, b1, c2, d2)) { a2 = a1; b2 = b1; }
                    else                        { a2 = c2; b2 = d2; }
                    a1 = c1; b1 = d1;
                } else {
                    if (better(c1, d1, a2, b2)) { a2 = c1; b2 = d1; }
                }
            }
            if (l15 == 0) {
                const int row = rowbase + w * 32 + m * 16 + lg * 4 + q;
                candi2[(row * NKS + ks) * 2 + 0] = b1;
                candi2[(row * NKS + ks) * 2 + 1] = b2;
            }
        }
}

// ------- fused refine (exact fp32 over 16 cands) + gather + loss -----------
// 4 waves/block, each wave handles 8 rows sequentially. Refine: lane =
// (cand 0..15) x (dim-group 0..3); after xor-16/32 sum + xor-8..1 argmin,
// ALL lanes hold the winning index. Gather: 64 lanes x float4.
__global__ void refine_gather(const float* __restrict__ X, const float* __restrict__ Et,
                              const int* __restrict__ cand,
                              float* __restrict__ out, float* __restrict__ partials) {
    const int w = threadIdx.x >> 6, l = threadIdx.x & 63;
    const int cs = l & 15, dg = l >> 4;
    const int row0 = blockIdx.x * 32 + w * 8;
    float lsum = 0.f;

#pragma unroll 1
    for (int rr = 0; rr < 8; ++rr) {
        const int row = row0 + rr;
        const int c = cand[row * 16 + cs];
        const float4* ep = (const float4*)(Et + (size_t)c * DIM + dg * 64);
        const float4* xp = (const float4*)(X + (size_t)row * DIM + dg * 64);
        float p = 0.f;
#pragma unroll
        for (int j = 0; j < 16; ++j) {
            const float4 e = ep[j];
            const float4 x = xp[j];
            p = fmaf(e.x, fmaf(-2.f, x.x, e.x), p);
            p = fmaf(e.y, fmaf(-2.f, x.y, e.y), p);
            p = fmaf(e.z, fmaf(-2.f, x.z, e.z), p);
            p = fmaf(e.w, fmaf(-2.f, x.w, e.w), p);
        }
        p += __shfl_xor(p, 16, 64);
        p += __shfl_xor(p, 32, 64);
        float v = p; int id = c;
#pragma unroll
        for (int m = 8; m >= 1; m >>= 1) {
            const float v2 = __shfl_xor(v, m, 64);
            const int  id2 = __shfl_xor(id, m, 64);
            if (v2 < v || (v2 == v && id2 < id)) { v = v2; id = id2; }
        }
        // gather + loss (all lanes agree on id)
        const float4 x = *(const float4*)(X + (size_t)row * DIM + l * 4);
        const float4 q = *(const float4*)(Et + (size_t)id * DIM + l * 4);
        *(float4*)(out + (size_t)row * DIM + l * 4) = q;
        const float d0 = x.x - q.x, d1 = x.y - q.y, d2 = x.z - q.z, d3 = x.w - q.w;
        lsum += d0 * d0 + d1 * d1 + d2 * d2 + d3 * d3;
    }
#pragma unroll
    for (int m = 32; m >= 1; m >>= 1) lsum += __shfl_xor(lsum, m, 64);
    __shared__ float ws4[4];
    if (l == 0) ws4[w] = lsum;
    __syncthreads();
    if (threadIdx.x == 0) partials[blockIdx.x] = (ws4[0] + ws4[1]) + (ws4[2] + ws4[3]);
}

// -------- fallback fp32 dist (round-1 proven path, used if ws too small) ---
__global__ void dist_fp32(const float* __restrict__ X, const float* __restrict__ E,
                          const float* __restrict__ esq,
                          float* __restrict__ candv, int* __restrict__ candi) {
    __shared__ float Xs[8][128];
    __shared__ float Es[8][128];
    const int t = threadIdx.x;
    const int tx = t & 15;
    const int ty = t >> 4;
    const int rowbase = blockIdx.x * 128;
    const int ks = blockIdx.y;

    float minv[8];
    int   mini[8];
#pragma unroll
    for (int i = 0; i < 8; ++i) { minv[i] = 3.4e38f; mini[i] = 0; }

    for (int kt = 0; kt < 8; ++kt) {
        const int kbase = ks * 1024 + kt * 128;
        float acc[8][8];
#pragma unroll
        for (int i = 0; i < 8; ++i)
#pragma unroll
            for (int j = 0; j < 8; ++j) acc[i][j] = 0.f;

        for (int dc = 0; dc < DIM / 8; ++dc) {
            const int d0 = dc * 8;
            {
                const int row = t >> 1;
                const int dsl = (t & 1) * 4;
                const float4 xv = *(const float4*)(X + (size_t)(rowbase + row) * DIM + d0 + dsl);
                Xs[dsl + 0][row] = xv.x; Xs[dsl + 1][row] = xv.y;
                Xs[dsl + 2][row] = xv.z; Xs[dsl + 3][row] = xv.w;
            }
            {
                const int dr = t >> 5;
                const int c4 = (t & 31) * 4;
                const float4 ev = *(const float4*)(E + (size_t)(d0 + dr) * K_CODES + kbase + c4);
                *(float4*)&Es[dr][c4] = ev;
            }
            __syncthreads();
#pragma unroll
            for (int d = 0; d < 8; ++d) {
                float xr[8], er[8];
                *(float4*)&xr[0] = *(const float4*)&Xs[d][ty * 8];
                *(float4*)&xr[4] = *(const float4*)&Xs[d][ty * 8 + 4];
                *(float4*)&er[0] = *(const float4*)&Es[d][tx * 8];
                *(float4*)&er[4] = *(const float4*)&Es[d][tx * 8 + 4];
#pragma unroll
                for (int i = 0; i < 8; ++i)
#pragma unroll
                    for (int j = 0; j < 8; ++j)
                        acc[i][j] = fmaf(xr[i], er[j], acc[i][j]);
            }
            __syncthreads();
        }
        float eq[8];
        *(float4*)&eq[0] = *(const float4*)(esq + kbase + tx * 8);
        *(float4*)&eq[4] = *(const float4*)(esq + kbase + tx * 8 + 4);
#pragma unroll
        for (int i = 0; i < 8; ++i)
#pragma unroll
            for (int j = 0; j < 8; ++j) {
                const float dist = fmaf(-2.f, acc[i][j], eq[j]);
                if (dist < minv[i]) { minv[i] = dist; mini[i] = kbase + tx * 8 + j; }
            }
    }
#pragma unroll
    for (int i = 0; i < 8; ++i) {
        float v = minv[i];
        int   id = mini[i];
#pragma unroll
        for (int m = 8; m >= 1; m >>= 1) {
            const float v2 = __shfl_xor(v, m, 64);
            const int   i2 = __shfl_xor(id, m, 64);
            if (v2 < v || (v2 == v && i2 < id)) { v = v2; id = i2; }
        }
        if (tx == 0) {
            const int row = rowbase + ty * 8 + i;
            candv[row * 4 + ks] = v;
            candi[row * 4 + ks] = id;
        }
    }
}

__global__ void gather_loss(const float* __restrict__ X, const float* __restrict__ E,
                            const float* __restrict__ candv, const int* __restrict__ candi,
                            float* __restrict__ out, float* __restrict__ partials,
                            int nks) {
    const int w = threadIdx.x >> 6;
    const int l = threadIdx.x & 63;
    const int rowbase = blockIdx.x * (N_ROWS / GATHER_BLOCKS);
    float lsum = 0.f;

    for (int rr = w; rr < N_ROWS / GATHER_BLOCKS; rr += 4) {
        const int row = rowbase + rr;
        float bv = candv[row * nks];
        int   bi = candi[row * nks];
        for (int s = 1; s < nks; ++s) {
            const float v = candv[row * nks + s];
            const int  id = candi[row * nks + s];
            if (v < bv || (v == bv && id < bi)) { bv = v; bi = id; }
        }
        const float4 x = *(const float4*)(X + (size_t)row * DIM + l * 4);
        const float q0 = E[(size_t)(l * 4 + 0) * K_CODES + bi];
        const float q1 = E[(size_t)(l * 4 + 1) * K_CODES + bi];
        const float q2 = E[(size_t)(l * 4 + 2) * K_CODES + bi];
        const float q3 = E[(size_t)(l * 4 + 3) * K_CODES + bi];
        float4 q; q.x = q0; q.y = q1; q.z = q2; q.w = q3;
        *(float4*)(out + (size_t)row * DIM + l * 4) = q;
        const float d0 = x.x - q0, d1 = x.y - q1, d2 = x.z - q2, d3 = x.w - q3;
        lsum += d0 * d0 + d1 * d1 + d2 * d2 + d3 * d3;
    }
#pragma unroll
    for (int m = 32; m >= 1; m >>= 1) lsum += __shfl_xor(lsum, m, 64);
    __shared__ float ws4[4];
    if (l == 0) ws4[w] = lsum;
    __syncthreads();
    if (threadIdx.x == 0) partials[blockIdx.x] = (ws4[0] + ws4[1]) + (ws4[2] + ws4[3]);
}

__global__ void finalize(const float* __restrict__ partials, float* __restrict__ out_loss,
                         int npart) {
    __shared__ double s[256];
    double a = 0.0;
    for (int i = threadIdx.x; i < npart; i += 256) a += (double)partials[i];
    s[threadIdx.x] = a;
    __syncthreads();
    for (int st = 128; st > 0; st >>= 1) {
        if (threadIdx.x < st) s[threadIdx.x] += s[threadIdx.x + st];
        __syncthreads();
    }
    if (threadIdx.x == 0)
        out_loss[0] = (float)(1.25 * s[0] / (double)(N_ROWS * DIM));
}

extern "C" void kernel_launch(void* const* d_in, const int* in_sizes, int n_in,
                              void* d_out, int out_size, void* d_ws, size_t ws_size,
                              hipStream_t stream) {
    const float* X = (const float*)d_in[0];
    const float* E = (const float*)d_in[1];
    float* out = (float*)d_out;

    if (ws_size >= (size_t)WS_NEEDED) {
        // ---------------- MFMA path ----------------
        ushort_t* Ehi      = (ushort_t*)((char*)d_ws + 0);
        ushort_t* Elo      = (ushort_t*)((char*)d_ws + 2097152);
        float*    Et       = (float*)   ((char*)d_ws + 0);        // after dist_mfma
        int*      candi2   = (int*)     ((char*)d_ws + 4194304);
        float*    esq      = (float*)   ((char*)d_ws + 6291456);
        float*    partials = (float*)   ((char*)d_ws + 6438912);
        ushort_t* Xh       = (ushort_t*)d_out;                    // 16.78 MB
        ushort_t* Xl       = Xh + (size_t)N_ROWS * DIM;           // 16.78 MB

        prep_x<<<(N_ROWS * DIM / 4) / 256, 256, 0, stream>>>(X, Xh, Xl);
        prep_e<<<dim3(K_CODES / 64, DIM / 64), 256, 0, stream>>>(E, Ehi, Elo);
        esq_kernel<<<K_CODES / 16, 256, 0, stream>>>(E, esq);
        dist_mfma<<<dim3(NKS, N_ROWS / 128), 256, 0, stream>>>(
            Xh, Xl, Ehi, Elo, esq, candi2);
        prep_et<<<dim3(K_CODES / 64, DIM / 64), 256, 0, stream>>>(E, Et);
        refine_gather<<<RG_BLOCKS, 256, 0, stream>>>(X, Et, candi2, out, partials);
        finalize<<<1, 256, 0, stream>>>(partials, out + (size_t)N_ROWS * DIM, RG_BLOCKS);
    } else {
        // ---------------- fallback: round-1 fp32 path (needs ~1.07 MB) -----
        float* esq      = (float*)((char*)d_ws + 0);
        float* candv    = (float*)((char*)d_ws + 16384);
        int*   candi    = (int*)  ((char*)d_ws + 540672);
        float* partials = (float*)((char*)d_ws + 1064960);

        esq_kernel<<<K_CODES / 16, 256, 0, stream>>>(E, esq);
        dist_fp32<<<dim3(N_ROWS / 128, 4), 256, 0, stream>>>(X, E, esq, candv, candi);
        gather_loss<<<GATHER_BLOCKS, 256, 0, stream>>>(X, E, candv, candi, out,
                                                       partials, 4);
        finalize<<<1, 256, 0, stream>>>(partials, out + (size_t)N_ROWS * DIM,
                                        GATHER_BLOCKS);
    }
}